// Round 5
// baseline (2635.756 us; speedup 1.0000x reference)
//
#include <hip/hip_runtime.h>

// ---------------------------------------------------------------------------
// snnBlock: T=4 timesteps of Alpha-neuron -> SConv2dLSTM -> per-step BN.
// x [4,8,64,48,48] f32 -> out [4,8,128,48,48] f32.
//
// Round-5 changes (vs round-4):
//  * conv inner loop uses float2 ext-vector accumulators -> v_pk_fma_f32
//    (2 fp32 FMA/instr, bit-exact): 48 pk-instr per window instead of 96.
//  * staging address math (div/mod + bounds + LDS offset) hoisted out of the
//    chunk loop (chunk-invariant): LOADC = 6 predicated global loads,
//    WRITEC = 6 ds_writes at precomputed offsets.
// ---------------------------------------------------------------------------

typedef float v2f __attribute__((ext_vector_type(2)));

#define T_ 4
#define B_ 8
#define CIN 64
#define COUT 128
#define H_ 48
#define W_ 48
#define HW (H_ * W_)          // 2304
#define CCOMB (CIN + COUT)    // 192
#define NGATE (4 * COUT)      // 512
#define NPIX (B_ * HW)        // 18432
#define KTOT (CCOMB * 9)      // 1728
#define WCHUNK (72 * 16)      // weight floats per chunk per 16-gch group

// ---- workspace layout (32-bit words) ----
#define LEN_SYNE (B_ * CIN * HW)    // 1179648
#define LEN_SYN2 (B_ * COUT * HW)   // 2359296
#define LEN_CNT  (T_ * COUT)        // 512
#define LEN_WT   (NGATE * KTOT)     // 884736

#define OFF_SYNE 0
#define OFF_SYNI (OFF_SYNE + LEN_SYNE)
#define OFF_SPK1 (OFF_SYNI + LEN_SYNE)
#define OFF_CNT  (OFF_SPK1 + LEN_SYNE)
#define ZERO_WORDS (OFF_CNT + LEN_CNT)        // syn_e, syn_i, spk1, cnt
#define OFF_SYN2 ZERO_WORDS
#define OFF_SPK2 (OFF_SYN2 + LEN_SYN2)
#define OFF_M2A  (OFF_SPK2 + LEN_SYN2)
#define OFF_M2B  (OFF_M2A + LEN_SYN2)
#define OFF_WT   (OFF_M2B + LEN_SYN2)
#define OFF_U    (OFF_WT + LEN_WT)            // u_s2[128], u_m2[128]

// ---------------------------------------------------------------------------
__global__ __launch_bounds__(256) void zero_ws_kernel(float* __restrict__ p, int n) {
    int i = blockIdx.x * 256 + threadIdx.x;
    if (i < n) p[i] = 0.0f;
}

// ---------------------------------------------------------------------------
// wt[g][k][j]: g = ocb*4+wid (32 groups), j = gate*4 + m, cout = cb+m,
// real oc = gate*COUT + cout, cb = (g>>2)*16 + (g&3)*4.
__global__ __launch_bounds__(256) void wt_transform_kernel(
        const float* __restrict__ w, float* __restrict__ wt) {
    int id = blockIdx.x * 256 + threadIdx.x;      // g*KTOT + k, 55296 total
    int g = id / KTOT, k = id - g * KTOT;
    int cb = (g >> 2) * 16 + (g & 3) * 4;
    float* dst = wt + (size_t)id * 16;
#pragma unroll
    for (int j = 0; j < 16; ++j) {
        int gate = j >> 2, cm = cb + (j & 3);
        dst[j] = w[((gate * COUT + cm) * KTOT) + k];
    }
}

// ---------------------------------------------------------------------------
// Alpha neuron (float4 vectorized): 294912 quads.
__global__ __launch_bounds__(256) void alpha_step_kernel(
        const float4* __restrict__ x_t,
        const float* __restrict__ p_alpha, const float* __restrict__ p_beta,
        const float* __restrict__ p_th1,
        float4* __restrict__ syn_e, float4* __restrict__ syn_i,
        float4* __restrict__ spk1) {
#pragma clang fp contract(off)
    int i = blockIdx.x * 256 + threadIdx.x;   // 294912 = 1152*256
    float a = fminf(fmaxf(p_alpha[0], 1e-6f), 1.0f - 1e-6f);
    float b = fminf(fmaxf(p_beta[0],  1e-6f), 1.0f - 1e-6f);
    float la = logf(a), lb = logf(b);
    float tau = la / (lb - la);
    float th1 = p_th1[0];

    float4 xv = x_t[i], e4 = syn_e[i], i4 = syn_i[i], s4 = spk1[i];
    float e, ii, m1;
    e = a * e4.x + xv.x; ii = b * i4.x - xv.x; m1 = tau * (e + ii) - s4.x * th1;
    e4.x = e; i4.x = ii; s4.x = (m1 - th1) > 0.0f ? 1.0f : 0.0f;
    e = a * e4.y + xv.y; ii = b * i4.y - xv.y; m1 = tau * (e + ii) - s4.y * th1;
    e4.y = e; i4.y = ii; s4.y = (m1 - th1) > 0.0f ? 1.0f : 0.0f;
    e = a * e4.z + xv.z; ii = b * i4.z - xv.z; m1 = tau * (e + ii) - s4.z * th1;
    e4.z = e; i4.z = ii; s4.z = (m1 - th1) > 0.0f ? 1.0f : 0.0f;
    e = a * e4.w + xv.w; ii = b * i4.w - xv.w; m1 = tau * (e + ii) - s4.w * th1;
    e4.w = e; i4.w = ii; s4.w = (m1 - th1) > 0.0f ? 1.0f : 0.0f;
    syn_e[i] = e4; syn_i[i] = i4; spk1[i] = s4;
}

// ---------------------------------------------------------------------------
// t=0 per-channel LSTM-from-bias: cc = bias (conv of all-zero comb).
__global__ void t0_u_kernel(const float* __restrict__ b_conv,
                            float* __restrict__ u) {
#pragma clang fp contract(off)
    int c = threadIdx.x;                       // 128 threads
    float gi = b_conv[c], gf = b_conv[COUT + c];
    float gg = b_conv[2 * COUT + c], go = b_conv[3 * COUT + c];
    float si = 1.0f / (1.0f + expf(-gi));
    float sf = 1.0f / (1.0f + expf(-gf));
    float so = 1.0f / (1.0f + expf(-go));
    float tg = tanhf(gg);
    float s2 = sf * 0.0f + si * tg;
    float m2 = so * tanhf(s2);
    u[c] = s2;
    u[COUT + c] = m2;
}

// t=0 fill: syn2, mem2(buf A), out(t=0)=bn_beta. Quad never crosses channel
// (HW divisible by 4).
__global__ __launch_bounds__(256) void t0_fill_kernel(
        const float* __restrict__ u, const float* __restrict__ bnb,
        float4* __restrict__ syn2, float4* __restrict__ m2a,
        float4* __restrict__ out0) {
    int i = blockIdx.x * 256 + threadIdx.x;    // 589824 = 2304*256
    int c = ((i * 4) / HW) % COUT;
    float s2 = u[c], m2 = u[COUT + c], bb = bnb[c];
    syn2[i] = make_float4(s2, s2, s2, s2);
    m2a[i]  = make_float4(m2, m2, m2, m2);
    out0[i] = make_float4(bb, bb, bb, bb);
}

// ---------------------------------------------------------------------------
// Fused conv(3x3 SAME, 192ch -> 512 gates) + LSTM + spike + count.
// Block: 256 thr = 4 waves; wave = 8x16 tile, 2 px/lane, 4 couts x 4 gates.
// Grid: (b 8) x (tile 18: 6 row x 3 col) x (ocb 8) = 1152 blocks.
__global__ __launch_bounds__(256) void conv_lstm_kernel(
        const float* __restrict__ spk1, const float* __restrict__ m2rd,
        const float* __restrict__ wt, const float* __restrict__ bias,
        const float* __restrict__ p_th2,
        float* __restrict__ syn2, float* __restrict__ m2wr,
        float* __restrict__ spk2, int* __restrict__ cnt) {
    __shared__ float ilds[2][1600];            // ping-pong 8ci x 10r x 20c

    const int bx   = blockIdx.x;
    const int ocb  = bx & 7;
    const int tile = (bx >> 3) % 18;
    const int b    = bx / 144;
    const int th0  = (tile / 3) * 8;
    const int tw0  = (tile % 3) * 16;

    const int tid  = threadIdx.x;
    const int wid  = __builtin_amdgcn_readfirstlane(tid >> 6);
    const int lane = tid & 63;
    const int r    = lane >> 3;                // tile row 0..7
    const int c2   = (lane & 7) * 2;           // output col pair base 0..14
    const int rc   = r * 20 + c2;              // LDS read base within a ci

    const float* __restrict__ wg = wt + (size_t)(ocb * 4 + wid) * (KTOT * 16);

    // ---- chunk-invariant staging precompute: i = tid + j*256 -> 8x10x18 ----
    int ldsoff[6], srcoff[6];
#pragma unroll
    for (int j = 0; j < 6; ++j) {
        int i = tid + j * 256;
        int ci = i / 180;
        int rem = i - ci * 180;
        int rr = rem / 18, cc = rem - (rem / 18) * 18;
        int gh = th0 + rr - 1, gw = tw0 + cc - 1;
        ldsoff[j] = ci * 200 + rr * 20 + cc;
        bool ok = (i < 1440) &&
                  ((unsigned)gh < (unsigned)H_) && ((unsigned)gw < (unsigned)W_);
        srcoff[j] = ok ? (ci * HW + gh * W_ + gw) : -1;
    }
    const bool w5 = (tid < 160);               // j=5 writes only i<1440

    v2f acc[16];
#pragma unroll
    for (int j = 0; j < 16; ++j) acc[j] = (v2f){0.0f, 0.0f};

    float st[6];
#define LOADC(cic_)                                                          \
    {                                                                        \
        const int ciBase = (cic_) * 8;                                       \
        const float* csrc = (ciBase < CIN)                                   \
            ? spk1 + (size_t)(b * CIN + ciBase) * HW                         \
            : m2rd + (size_t)(b * COUT + (ciBase - CIN)) * HW;               \
        _Pragma("unroll")                                                    \
        for (int j = 0; j < 6; ++j) {                                        \
            float v = 0.0f;                                                  \
            if (srcoff[j] >= 0) v = csrc[srcoff[j]];                         \
            st[j] = v;                                                       \
        }                                                                    \
    }
#define WRITEC(buf_)                                                         \
    {                                                                        \
        float* bp = &ilds[buf_][0];                                          \
        _Pragma("unroll")                                                    \
        for (int j = 0; j < 5; ++j) bp[ldsoff[j]] = st[j];                   \
        if (w5) bp[ldsoff[5]] = st[5];                                       \
    }

    LOADC(0);
    for (int cic = 0; cic < 24; ++cic) {
        const int buf = cic & 1;
        WRITEC(buf);
        __syncthreads();
        if (cic < 23) LOADC(cic + 1);          // prefetch under compute

        const float* wchunk = wg + cic * WCHUNK;
        const float* bufp = &ilds[buf][0];
#pragma unroll 2
        for (int ci = 0; ci < 8; ++ci) {
#pragma unroll
            for (int kh = 0; kh < 3; ++kh) {
                const float* row = bufp + ci * 200 + kh * 20 + rc;
                const float2 a0 = *(const float2*)(row);
                const float2 a1 = *(const float2*)(row + 2);
                const v2f i0 = {a0.x, a0.y};
                const v2f i1 = {a0.y, a1.x};
                const v2f i2 = {a1.x, a1.y};
                const float* wrow = wchunk + (ci * 9 + kh * 3) * 16;
#pragma unroll
                for (int j = 0; j < 16; ++j) acc[j] += i0 * wrow[j];
#pragma unroll
                for (int j = 0; j < 16; ++j) acc[j] += i1 * wrow[16 + j];
#pragma unroll
                for (int j = 0; j < 16; ++j) acc[j] += i2 * wrow[32 + j];
            }
        }
        // next WRITEC targets the other buffer; loop-top barrier orders it.
    }

    // ---- fused LSTM epilogue (2 pixels via float2) ----
    {
#pragma clang fp contract(off)
        const float th2 = p_th2[0];
        const int cb = ocb * 16 + wid * 4;
        const int h = th0 + r, ww = tw0 + c2;
#pragma unroll
        for (int m = 0; m < 4; ++m) {
            const int cm = cb + m;
            const float b0 = bias[cm],            b1 = bias[COUT + cm];
            const float b2 = bias[2 * COUT + cm], b3 = bias[3 * COUT + cm];
            const int idx = ((b * COUT + cm) * H_ + h) * W_ + ww;
            const float2 s2old = *(const float2*)&syn2[idx];
            float2 s2n, m2n, spn;
            {
                float gi = acc[m].x + b0, gf = acc[4 + m].x + b1;
                float gg = acc[8 + m].x + b2, go = acc[12 + m].x + b3;
                float si = 1.0f / (1.0f + expf(-gi));
                float sf = 1.0f / (1.0f + expf(-gf));
                float so = 1.0f / (1.0f + expf(-go));
                float tg = tanhf(gg);
                float s2 = sf * s2old.x + si * tg;
                float m2 = so * tanhf(s2);
                s2n.x = s2; m2n.x = m2;
                spn.x = (m2 - th2) > 0.0f ? 1.0f : 0.0f;
            }
            {
                float gi = acc[m].y + b0, gf = acc[4 + m].y + b1;
                float gg = acc[8 + m].y + b2, go = acc[12 + m].y + b3;
                float si = 1.0f / (1.0f + expf(-gi));
                float sf = 1.0f / (1.0f + expf(-gf));
                float so = 1.0f / (1.0f + expf(-go));
                float tg = tanhf(gg);
                float s2 = sf * s2old.y + si * tg;
                float m2 = so * tanhf(s2);
                s2n.y = s2; m2n.y = m2;
                spn.y = (m2 - th2) > 0.0f ? 1.0f : 0.0f;
            }
            *(float2*)&syn2[idx] = s2n;
            *(float2*)&m2wr[idx] = m2n;
            *(float2*)&spk2[idx] = spn;
            unsigned long long mk0 = __ballot(spn.x > 0.0f);
            unsigned long long mk1 = __ballot(spn.y > 0.0f);
            if (lane == 0)
                atomicAdd(&cnt[cm], (int)(__popcll(mk0) + __popcll(mk1)));
        }
    }
#undef LOADC
#undef WRITEC
}

// ---------------------------------------------------------------------------
// BN of the binary spike field (float4): mu = cnt/NPIX exact, var = mu - mu^2.
__global__ __launch_bounds__(256) void bn_step_kernel(
        const float4* __restrict__ spk2, const int* __restrict__ cnt,
        const float* __restrict__ gamma, const float* __restrict__ bnb,
        float4* __restrict__ out) {
#pragma clang fp contract(off)
    int i = blockIdx.x * 256 + threadIdx.x;    // 589824 = 2304*256
    int c = ((i * 4) / HW) % COUT;
    float mu  = (float)cnt[c] / (float)NPIX;
    float var = mu - mu * mu;
    float rs  = rsqrtf(var + 1e-5f);
    float g = gamma[c], bb = bnb[c];
    float4 s = spk2[i];
    out[i] = make_float4(g * (s.x - mu) * rs + bb, g * (s.y - mu) * rs + bb,
                         g * (s.z - mu) * rs + bb, g * (s.w - mu) * rs + bb);
}

// ---------------------------------------------------------------------------
extern "C" void kernel_launch(void* const* d_in, const int* in_sizes, int n_in,
                              void* d_out, int out_size, void* d_ws, size_t ws_size,
                              hipStream_t stream) {
    const float* x       = (const float*)d_in[0];
    const float* p_alpha = (const float*)d_in[1];
    const float* p_beta  = (const float*)d_in[2];
    const float* p_th1   = (const float*)d_in[3];
    const float* p_th2   = (const float*)d_in[4];
    const float* w_conv  = (const float*)d_in[5];
    const float* b_conv  = (const float*)d_in[6];
    const float* gamma   = (const float*)d_in[7];
    const float* bn_beta = (const float*)d_in[8];
    float* out = (float*)d_out;

    float* wsf   = (float*)d_ws;
    float* syn_e = wsf + OFF_SYNE;
    float* syn_i = wsf + OFF_SYNI;
    float* spk1  = wsf + OFF_SPK1;
    int*   cnt   = (int*)(wsf + OFF_CNT);
    float* syn2  = wsf + OFF_SYN2;
    float* spk2  = wsf + OFF_SPK2;
    float* m2a   = wsf + OFF_M2A;
    float* m2b   = wsf + OFF_M2B;
    float* wt    = wsf + OFF_WT;
    float* u     = wsf + OFF_U;

    zero_ws_kernel<<<(ZERO_WORDS + 255) / 256, 256, 0, stream>>>(wsf, ZERO_WORDS);
    wt_transform_kernel<<<(32 * KTOT) / 256, 256, 0, stream>>>(w_conv, wt);

    // ---- t = 0 (conv of all-zero comb == bias; BN of uniform == bn_beta) ----
    alpha_step_kernel<<<LEN_SYNE / 1024, 256, 0, stream>>>(
        (const float4*)x, p_alpha, p_beta, p_th1,
        (float4*)syn_e, (float4*)syn_i, (float4*)spk1);
    t0_u_kernel<<<1, COUT, 0, stream>>>(b_conv, u);
    t0_fill_kernel<<<LEN_SYN2 / 1024, 256, 0, stream>>>(
        u, bn_beta, (float4*)syn2, (float4*)m2a, (float4*)out);

    // ---- t = 1..3 ----
    float* m2buf[2] = {m2a, m2b};
    for (int t = 1; t < T_; ++t) {
        alpha_step_kernel<<<LEN_SYNE / 1024, 256, 0, stream>>>(
            (const float4*)(x + (size_t)t * LEN_SYNE), p_alpha, p_beta, p_th1,
            (float4*)syn_e, (float4*)syn_i, (float4*)spk1);
        conv_lstm_kernel<<<1152, 256, 0, stream>>>(
            spk1, m2buf[(t - 1) & 1], wt, b_conv, p_th2,
            syn2, m2buf[t & 1], spk2, cnt + t * COUT);
        bn_step_kernel<<<LEN_SYN2 / 1024, 256, 0, stream>>>(
            (const float4*)spk2, cnt + t * COUT, gamma, bn_beta,
            (float4*)(out + (size_t)t * LEN_SYN2));
    }
}

// Round 7
// 1160.349 us; speedup vs baseline: 2.2715x; 2.2715x over previous
//
#include <hip/hip_runtime.h>

// ---------------------------------------------------------------------------
// snnBlock, round 7: MFMA (bf16 Dekker-split) conv + fused LSTM.
// Identical to round 6 except the LDS staging granularity bug is fixed:
// uint4 = 8 u16 (16 B), so each 32-channel pixel row needs 4 uint4 chunks
// (was written as 2 "halves" of 16 -> channels 8-15/24-31 were stale garbage).
// ---------------------------------------------------------------------------

typedef unsigned short u16;
typedef __attribute__((ext_vector_type(8))) __bf16 bf16x8;
typedef __attribute__((ext_vector_type(4))) float   f32x4;

#define T_ 4
#define B_ 8
#define CIN 64
#define COUT 128
#define H_ 48
#define W_ 48
#define HW 2304
#define NPIX 18432
#define KTOT 1728
#define WTPL 884736            // elements per weight plane

// ---- workspace layout (32-bit words) ----
#define OFF_SYNE  0
#define OFF_SYNI  1179648
#define OFF_SPK1H 2359296      // bf16 [B][HW][64]
#define OFF_CNT   2949120      // int [T][128]
#define ZERO_W    2949632
#define OFF_SYN2  2949632      // f32 [B][128][HW]
#define OFF_SPK2H 5308928      // bf16 [B][HW][128]
#define OFF_M2H0  6488576      // bf16 [B][HW][128] x6 (h,l,l2 x 2 buffers)
#define OFF_M2H1  7668224
#define OFF_M2L0  8847872
#define OFF_M2L1  10027520
#define OFF_M2L20 11207168
#define OFF_M2L21 12386816
#define OFF_WT    13566464     // bf16 [3][884736]
#define OFF_U     14893568     // f32 us2[128]; u16 uh/ul/ul2[128]

static __device__ __forceinline__ u16 bfbits(float f) {
    __bf16 h = (__bf16)f; u16 u; __builtin_memcpy(&u, &h, 2); return u;
}
static __device__ __forceinline__ float bff(u16 u) {
    __bf16 h; __builtin_memcpy(&h, &u, 2); return (float)h;
}
static __device__ __forceinline__ f32x4 MFMA(bf16x8 a, bf16x8 b, f32x4 c) {
    return __builtin_amdgcn_mfma_f32_16x16x32_bf16(a, b, c, 0, 0, 0);
}

// ---------------------------------------------------------------------------
__global__ __launch_bounds__(256) void zero_ws_kernel(float* __restrict__ p, int n) {
    int i = blockIdx.x * 256 + threadIdx.x;
    if (i < n) p[i] = 0.0f;
}

// ---------------------------------------------------------------------------
// Weight transform: w[oc=gate*128+cout][ch][kh][kw] -> 3 bf16 planes in
// fragment order: plane[((nt*6+ck)*9+tap)*512 + lane*8 + j],
// nt = cg*4+gate, lane = (kg<<4)|coutsub, ch = ck*32 + kg*8 + j.
__global__ __launch_bounds__(256) void wt_transform_kernel(
        const float* __restrict__ w, u16* __restrict__ wt) {
    int id = blockIdx.x * 256 + threadIdx.x;      // 110592
    int lane = id & 63;
    int rest = id >> 6;                            // 1728
    int tap = rest % 9;
    int rest2 = rest / 9;                          // 192
    int ck = rest2 % 6, nt = rest2 / 6;            // nt 0..31
    int gate = nt & 3, cg = nt >> 2;
    int coutsub = lane & 15, kgl = lane >> 4;
    int oc = gate * COUT + cg * 16 + coutsub;
    int kh = tap / 3, kw = tap - kh * 3;
    size_t dst = ((size_t)(nt * 6 + ck) * 9 + tap) * 512 + lane * 8;
#pragma unroll
    for (int j = 0; j < 8; ++j) {
        int ch = ck * 32 + kgl * 8 + j;
        float wv = w[((oc * 192 + ch) * 3 + kh) * 3 + kw];
        float hh = (float)(__bf16)wv;
        float r1 = wv - hh;
        float ll = (float)(__bf16)r1;
        float r2 = r1 - ll;
        wt[dst + j]            = bfbits(hh);
        wt[WTPL + dst + j]     = bfbits(ll);
        wt[2 * WTPL + dst + j] = bfbits(r2);
    }
}

// ---------------------------------------------------------------------------
// Alpha neuron; states ch-major f32 (float4); spk1 written pixel-major bf16.
__global__ __launch_bounds__(256) void alpha_step_kernel(
        const float4* __restrict__ x_t,
        const float* __restrict__ p_alpha, const float* __restrict__ p_beta,
        const float* __restrict__ p_th1,
        float4* __restrict__ syn_e, float4* __restrict__ syn_i,
        u16* __restrict__ spk1h) {
#pragma clang fp contract(off)
    int q = blockIdx.x * 256 + threadIdx.x;       // 294912 quads
    float a = fminf(fmaxf(p_alpha[0], 1e-6f), 1.0f - 1e-6f);
    float b = fminf(fmaxf(p_beta[0],  1e-6f), 1.0f - 1e-6f);
    float la = logf(a), lb = logf(b);
    float tau = la / (lb - la);
    float th1 = p_th1[0];

    int bc = q / 576;                              // b*64 + c
    int hw0 = (q - bc * 576) * 4;
    int bb = bc >> 6, c = bc & 63;
    u16* sp = spk1h + ((size_t)bb * HW + hw0) * 64 + c;

    float4 xv = x_t[q], e4 = syn_e[q], i4 = syn_i[q];
    float pr0 = bff(sp[0]), pr1 = bff(sp[64]), pr2 = bff(sp[128]), pr3 = bff(sp[192]);
    float e, ii, m1;
    u16 s0, s1, s2, s3;
    e = a * e4.x + xv.x; ii = b * i4.x - xv.x; m1 = tau * (e + ii) - pr0 * th1;
    e4.x = e; i4.x = ii; s0 = (m1 - th1) > 0.0f ? 0x3F80u : 0u;
    e = a * e4.y + xv.y; ii = b * i4.y - xv.y; m1 = tau * (e + ii) - pr1 * th1;
    e4.y = e; i4.y = ii; s1 = (m1 - th1) > 0.0f ? 0x3F80u : 0u;
    e = a * e4.z + xv.z; ii = b * i4.z - xv.z; m1 = tau * (e + ii) - pr2 * th1;
    e4.z = e; i4.z = ii; s2 = (m1 - th1) > 0.0f ? 0x3F80u : 0u;
    e = a * e4.w + xv.w; ii = b * i4.w - xv.w; m1 = tau * (e + ii) - pr3 * th1;
    e4.w = e; i4.w = ii; s3 = (m1 - th1) > 0.0f ? 0x3F80u : 0u;
    syn_e[q] = e4; syn_i[q] = i4;
    sp[0] = s0; sp[64] = s1; sp[128] = s2; sp[192] = s3;
}

// ---------------------------------------------------------------------------
// t=0: conv(all-zero input) = bias -> per-channel LSTM values.
__global__ void t0_u_kernel(const float* __restrict__ b_conv, float* __restrict__ u) {
#pragma clang fp contract(off)
    int c = threadIdx.x;                           // 128
    float gi = b_conv[c], gf = b_conv[COUT + c];
    float gg = b_conv[2 * COUT + c], go = b_conv[3 * COUT + c];
    float si = 1.0f / (1.0f + expf(-gi));
    float sf = 1.0f / (1.0f + expf(-gf));
    float so = 1.0f / (1.0f + expf(-go));
    float tg = tanhf(gg);
    float s2 = sf * 0.0f + si * tg;
    float m2 = so * tanhf(s2);
    u[c] = s2;
    u16* uh = (u16*)(u + 128);
    float hh = (float)(__bf16)m2;
    float r1 = m2 - hh;
    float ll = (float)(__bf16)r1;
    float r2 = r1 - ll;
    uh[c] = bfbits(hh); uh[128 + c] = bfbits(ll); uh[256 + c] = bfbits(r2);
}

// t=0 fill (ch-major): syn2 = u_s2[c], out(t0) = bn_beta[c].
__global__ __launch_bounds__(256) void t0_fillA_kernel(
        const float* __restrict__ u, const float* __restrict__ bnb,
        float4* __restrict__ syn2, float4* __restrict__ out0) {
    int i = blockIdx.x * 256 + threadIdx.x;        // 589824 quads
    int c = ((i * 4) / HW) % COUT;
    float s2 = u[c], bb = bnb[c];
    syn2[i] = make_float4(s2, s2, s2, s2);
    out0[i] = make_float4(bb, bb, bb, bb);
}

// t=0 fill (pixel-major): mem2 split planes (read buffer for t=1).
__global__ __launch_bounds__(256) void t0_fillB_kernel(
        const float* __restrict__ u,
        u16* __restrict__ mh, u16* __restrict__ ml, u16* __restrict__ ml2) {
    int i = blockIdx.x * 256 + threadIdx.x;        // 589824
    int pg = i >> 5, c0 = (i & 31) * 4;
    const u16* uh = (const u16*)(u + 128);
    uint2 vh  = *(const uint2*)(uh + c0);
    uint2 vl  = *(const uint2*)(uh + 128 + c0);
    uint2 vl2 = *(const uint2*)(uh + 256 + c0);
    *(uint2*)(mh  + (size_t)pg * 128 + c0) = vh;
    *(uint2*)(ml  + (size_t)pg * 128 + c0) = vl;
    *(uint2*)(ml2 + (size_t)pg * 128 + c0) = vl2;
}

// ---------------------------------------------------------------------------
// MFMA conv + fused LSTM. Block: 4 waves, M=64 px (rows h0..h0+3 x 16 cols),
// each wave one coutgrp (N=64 = 4 gates x 16 couts). Grid 576:
// bx = nh*288 + mt*8 + b  (nh slow -> XCD weight-slice locality).
__global__ __launch_bounds__(256) void conv_lstm_mfma(
        const u16* __restrict__ spk1h,
        const u16* __restrict__ m2h, const u16* __restrict__ m2l,
        const u16* __restrict__ m2l2,
        const u16* __restrict__ wt,
        const float* __restrict__ bias, const float* __restrict__ p_th2,
        float* __restrict__ syn2,
        u16* __restrict__ o_m2h, u16* __restrict__ o_m2l, u16* __restrict__ o_m2l2,
        u16* __restrict__ spk2h, int* __restrict__ cnt) {
    __shared__ u16 alds[3][4320];                  // [plane][6 rows][18 cols][40 ch]

    const int bx = blockIdx.x;
    const int nh = bx / 288;
    const int rm = bx - nh * 288;
    const int mt = rm >> 3, b = rm & 7;
    const int mt3 = mt / 3;
    const int h0 = mt3 * 4, w0 = (mt - mt3 * 3) * 16;

    const int tid = threadIdx.x;
    const int wn  = tid >> 6;
    const int lane = tid & 63;
    const int m16 = lane & 15;
    const int kg  = lane >> 4;
    const size_t pxbase = (size_t)b * HW;

    f32x4 acc[4][4];
#pragma unroll
    for (int mf = 0; mf < 4; ++mf)
#pragma unroll
        for (int g = 0; g < 4; ++g) acc[mf][g] = (f32x4){0.f, 0.f, 0.f, 0.f};

    const int ntb = nh * 16 + wn * 4;

    // ---------------- binary chunks (spk1, ck 0..1): 3-term ----------------
    for (int ck = 0; ck < 2; ++ck) {
        __syncthreads();
        {
            const u16* s0 = spk1h + pxbase * 64 + ck * 32;
            // 108 px x 4 quarters; uint4 = 8 u16 (16 B)
            for (int i = tid; i < 432; i += 256) {
                int px = i >> 2, qt = i & 3;
                int rr = px / 18, cc = px - rr * 18;
                int gh = h0 - 1 + rr, gw = w0 - 1 + cc;
                uint4 v = make_uint4(0u, 0u, 0u, 0u);
                if ((unsigned)gh < 48u && (unsigned)gw < 48u)
                    v = *(const uint4*)(s0 + (size_t)(gh * 48 + gw) * 64 + qt * 8);
                *(uint4*)&alds[0][px * 40 + qt * 8] = v;
            }
        }
        __syncthreads();
#pragma unroll
        for (int kh = 0; kh < 3; ++kh)
#pragma unroll
        for (int kw = 0; kw < 3; ++kw) {
            bf16x8 Ah[4];
#pragma unroll
            for (int mf = 0; mf < 4; ++mf)
                Ah[mf] = *(const bf16x8*)&alds[0][((mf + kh) * 18 + m16 + kw) * 40 + kg * 8];
#pragma unroll
            for (int g = 0; g < 4; ++g) {
                const size_t bo = ((size_t)((ntb + g) * 6 + ck) * 9 + (kh * 3 + kw)) * 512 + lane * 8;
                bf16x8 Bh  = *(const bf16x8*)(wt + bo);
                bf16x8 Bl  = *(const bf16x8*)(wt + WTPL + bo);
                bf16x8 Bl2 = *(const bf16x8*)(wt + 2 * WTPL + bo);
#pragma unroll
                for (int mf = 0; mf < 4; ++mf) acc[mf][g] = MFMA(Ah[mf], Bh,  acc[mf][g]);
#pragma unroll
                for (int mf = 0; mf < 4; ++mf) acc[mf][g] = MFMA(Ah[mf], Bl,  acc[mf][g]);
#pragma unroll
                for (int mf = 0; mf < 4; ++mf) acc[mf][g] = MFMA(Ah[mf], Bl2, acc[mf][g]);
            }
        }
    }

    // ---------------- mem2 chunks (ck 2..5): 7-term ----------------
    for (int ck = 2; ck < 6; ++ck) {
        __syncthreads();
        {
            const int ch0 = (ck - 2) * 32;
            const u16* s0 = m2h  + pxbase * 128 + ch0;
            const u16* s1 = m2l  + pxbase * 128 + ch0;
            const u16* s2 = m2l2 + pxbase * 128 + ch0;
            // 3 planes x 108 px x 4 quarters
            for (int i = tid; i < 1296; i += 256) {
                int pl = i / 432;
                int r = i - pl * 432;
                int px = r >> 2, qt = r & 3;
                int rr = px / 18, cc = px - rr * 18;
                int gh = h0 - 1 + rr, gw = w0 - 1 + cc;
                uint4 v = make_uint4(0u, 0u, 0u, 0u);
                if ((unsigned)gh < 48u && (unsigned)gw < 48u) {
                    const u16* sp = (pl == 0 ? s0 : (pl == 1 ? s1 : s2));
                    v = *(const uint4*)(sp + (size_t)(gh * 48 + gw) * 128 + qt * 8);
                }
                *(uint4*)&alds[pl][px * 40 + qt * 8] = v;
            }
        }
        __syncthreads();
#pragma unroll
        for (int kh = 0; kh < 3; ++kh)
#pragma unroll
        for (int kw = 0; kw < 3; ++kw) {
            bf16x8 Ah[4], Al[4], Al2[4];
#pragma unroll
            for (int mf = 0; mf < 4; ++mf) {
                const int ai = ((mf + kh) * 18 + m16 + kw) * 40 + kg * 8;
                Ah[mf]  = *(const bf16x8*)&alds[0][ai];
                Al[mf]  = *(const bf16x8*)&alds[1][ai];
                Al2[mf] = *(const bf16x8*)&alds[2][ai];
            }
#pragma unroll
            for (int g = 0; g < 4; ++g) {
                const size_t bo = ((size_t)((ntb + g) * 6 + ck) * 9 + (kh * 3 + kw)) * 512 + lane * 8;
                bf16x8 Bh  = *(const bf16x8*)(wt + bo);
                bf16x8 Bl  = *(const bf16x8*)(wt + WTPL + bo);
                bf16x8 Bl2 = *(const bf16x8*)(wt + 2 * WTPL + bo);
#pragma unroll
                for (int mf = 0; mf < 4; ++mf) acc[mf][g] = MFMA(Ah[mf],  Bh,  acc[mf][g]);
#pragma unroll
                for (int mf = 0; mf < 4; ++mf) acc[mf][g] = MFMA(Ah[mf],  Bl,  acc[mf][g]);
#pragma unroll
                for (int mf = 0; mf < 4; ++mf) acc[mf][g] = MFMA(Ah[mf],  Bl2, acc[mf][g]);
#pragma unroll
                for (int mf = 0; mf < 4; ++mf) acc[mf][g] = MFMA(Al[mf],  Bh,  acc[mf][g]);
#pragma unroll
                for (int mf = 0; mf < 4; ++mf) acc[mf][g] = MFMA(Al[mf],  Bl,  acc[mf][g]);
#pragma unroll
                for (int mf = 0; mf < 4; ++mf) acc[mf][g] = MFMA(Al2[mf], Bh,  acc[mf][g]);
#pragma unroll
                for (int mf = 0; mf < 4; ++mf) acc[mf][g] = MFMA(Al2[mf], Bl,  acc[mf][g]);
            }
        }
    }

    // ---------------- fused LSTM epilogue ----------------
    {
#pragma clang fp contract(off)
        const float th2 = p_th2[0];
        const int cg = nh * 4 + wn;
        const int cout = cg * 16 + m16;
        const float b0 = bias[cout],            b1 = bias[COUT + cout];
        const float b2 = bias[2 * COUT + cout], b3 = bias[3 * COUT + cout];
        int sc = 0;
#pragma unroll
        for (int mf = 0; mf < 4; ++mf) {
            const int h = h0 + mf;
#pragma unroll
            for (int reg = 0; reg < 4; ++reg) {
                const int w = w0 + kg * 4 + reg;
                float gi = acc[mf][0][reg] + b0;
                float gf = acc[mf][1][reg] + b1;
                float gg = acc[mf][2][reg] + b2;
                float go = acc[mf][3][reg] + b3;
                float si = 1.0f / (1.0f + expf(-gi));
                float sf = 1.0f / (1.0f + expf(-gf));
                float so = 1.0f / (1.0f + expf(-go));
                float tg = tanhf(gg);
                const int sidx = ((b * COUT + cout) * 48 + h) * 48 + w;
                float s2 = sf * syn2[sidx] + si * tg;
                float m2 = so * tanhf(s2);
                syn2[sidx] = s2;
                float hh = (float)(__bf16)m2;
                float r1 = m2 - hh;
                float ll = (float)(__bf16)r1;
                float r2 = r1 - ll;
                const size_t pix = (pxbase + (size_t)(h * 48 + w)) * 128 + cout;
                o_m2h[pix]  = bfbits(hh);
                o_m2l[pix]  = bfbits(ll);
                o_m2l2[pix] = bfbits(r2);
                bool sp = (m2 - th2) > 0.0f;
                spk2h[pix] = sp ? 0x3F80u : 0u;
                sc += sp ? 1 : 0;
            }
        }
        int t1 = sc + __shfl_xor(sc, 16);
        int tot = t1 + __shfl_xor(t1, 32);
        if (lane < 16) atomicAdd(&cnt[cg * 16 + lane], tot);
    }
}

// ---------------------------------------------------------------------------
// BN of binary spikes: mu = cnt/NPIX exact, var = mu - mu^2; reads pm bf16.
__global__ __launch_bounds__(256) void bn_step_kernel(
        const u16* __restrict__ spk2h, const int* __restrict__ cnt,
        const float* __restrict__ gamma, const float* __restrict__ bnb,
        float4* __restrict__ out) {
#pragma clang fp contract(off)
    int i = blockIdx.x * 256 + threadIdx.x;        // 589824 quads (ch-major out)
    int e = i * 4;
    int tmp = e / HW;                               // b*128 + c
    int bb = tmp >> 7, c = tmp & 127;
    int hw0 = e - tmp * HW;
    const u16* sp = spk2h + ((size_t)bb * HW + hw0) * 128 + c;
    float mu  = (float)cnt[c] / (float)NPIX;
    float var = mu - mu * mu;
    float rs  = rsqrtf(var + 1e-5f);
    float g = gamma[c], bv = bnb[c];
    float s0 = bff(sp[0]), s1 = bff(sp[128]), s2 = bff(sp[256]), s3 = bff(sp[384]);
    out[i] = make_float4(g * (s0 - mu) * rs + bv, g * (s1 - mu) * rs + bv,
                         g * (s2 - mu) * rs + bv, g * (s3 - mu) * rs + bv);
}

// ---------------------------------------------------------------------------
extern "C" void kernel_launch(void* const* d_in, const int* in_sizes, int n_in,
                              void* d_out, int out_size, void* d_ws, size_t ws_size,
                              hipStream_t stream) {
    const float* x       = (const float*)d_in[0];
    const float* p_alpha = (const float*)d_in[1];
    const float* p_beta  = (const float*)d_in[2];
    const float* p_th1   = (const float*)d_in[3];
    const float* p_th2   = (const float*)d_in[4];
    const float* w_conv  = (const float*)d_in[5];
    const float* b_conv  = (const float*)d_in[6];
    const float* gamma   = (const float*)d_in[7];
    const float* bn_beta = (const float*)d_in[8];
    float* out = (float*)d_out;

    float* wsf   = (float*)d_ws;
    float* syn_e = wsf + OFF_SYNE;
    float* syn_i = wsf + OFF_SYNI;
    u16*   spk1h = (u16*)(wsf + OFF_SPK1H);
    int*   cnt   = (int*)(wsf + OFF_CNT);
    float* syn2  = wsf + OFF_SYN2;
    u16*   spk2h = (u16*)(wsf + OFF_SPK2H);
    u16*   mh[2]  = {(u16*)(wsf + OFF_M2H0),  (u16*)(wsf + OFF_M2H1)};
    u16*   ml[2]  = {(u16*)(wsf + OFF_M2L0),  (u16*)(wsf + OFF_M2L1)};
    u16*   ml2[2] = {(u16*)(wsf + OFF_M2L20), (u16*)(wsf + OFF_M2L21)};
    u16*   wt    = (u16*)(wsf + OFF_WT);
    float* u     = wsf + OFF_U;

    zero_ws_kernel<<<ZERO_W / 256, 256, 0, stream>>>(wsf, ZERO_W);
    wt_transform_kernel<<<432, 256, 0, stream>>>(w_conv, wt);

    // ---- t = 0 (algebraic) ----
    alpha_step_kernel<<<1152, 256, 0, stream>>>(
        (const float4*)x, p_alpha, p_beta, p_th1,
        (float4*)syn_e, (float4*)syn_i, spk1h);
    t0_u_kernel<<<1, COUT, 0, stream>>>(b_conv, u);
    t0_fillA_kernel<<<2304, 256, 0, stream>>>(
        u, bn_beta, (float4*)syn2, (float4*)out);
    t0_fillB_kernel<<<2304, 256, 0, stream>>>(u, mh[0], ml[0], ml2[0]);

    // ---- t = 1..3 ----
    for (int t = 1; t < T_; ++t) {
        const int rd = (t - 1) & 1, wr = t & 1;
        alpha_step_kernel<<<1152, 256, 0, stream>>>(
            (const float4*)(x + (size_t)t * 1179648), p_alpha, p_beta, p_th1,
            (float4*)syn_e, (float4*)syn_i, spk1h);
        conv_lstm_mfma<<<576, 256, 0, stream>>>(
            spk1h, mh[rd], ml[rd], ml2[rd], wt, b_conv, p_th2,
            syn2, mh[wr], ml[wr], ml2[wr], spk2h, cnt + t * COUT);
        bn_step_kernel<<<2304, 256, 0, stream>>>(
            spk2h, cnt + t * COUT, gamma, bn_beta,
            (float4*)(out + (size_t)t * 2359296));
    }
}

// Round 8
// 950.698 us; speedup vs baseline: 2.7724x; 1.2205x over previous
//
#include <hip/hip_runtime.h>

// ---------------------------------------------------------------------------
// snnBlock, round 8: MFMA conv (bf16 Dekker-split, verified r7) with the
// LSTM epilogue decoupled into its own kernel so the conv grid can be
// N-split per wave (1 nt instead of 4) -> 4x more waves, 4x fewer acc VGPRs.
//  * conv writes raw gate sums to cc f32 [b][nt*16+m16][HW] (dwordx4 stores)
//  * lstm_step reads cc (+bias), updates syn2, writes m2 h/l/l2 planes,
//    spk2, and exact per-channel spike counts
//  * m2 planes single-buffered now (conv reads, lstm writes, stream-ordered)
// ---------------------------------------------------------------------------

typedef unsigned short u16;
typedef __attribute__((ext_vector_type(8))) __bf16 bf16x8;
typedef __attribute__((ext_vector_type(4))) float   f32x4;

#define T_ 4
#define B_ 8
#define CIN 64
#define COUT 128
#define H_ 48
#define W_ 48
#define HW 2304
#define NPIX 18432
#define KTOT 1728
#define WTPL 884736            // elements per weight plane

// ---- workspace layout (32-bit words) ----
#define OFF_SYNE  0
#define OFF_SYNI  1179648
#define OFF_SPK1H 2359296      // bf16 [B][HW][64]
#define OFF_CNT   2949120      // int [T][128]
#define ZERO_W    2949632
#define OFF_SYN2  2949632      // f32 [B][128][HW]
#define OFF_SPK2H 5308928      // bf16 [B][HW][128]
#define OFF_M2H   6488576      // bf16 [B][HW][128] (single-buffered)
#define OFF_M2L   7078400
#define OFF_M2L2  7668224
#define OFF_WT    8258048      // bf16 [3][884736]
#define OFF_U     9585152      // f32 us2[128]; u16 uh/ul/ul2[3][128]
#define OFF_CC    9585664      // f32 [B][512][HW] raw gate sums
// end = 19,022,848 words = 76.1 MB (<= 80.2 MB proven in round 1)

static __device__ __forceinline__ u16 bfbits(float f) {
    __bf16 h = (__bf16)f; u16 u; __builtin_memcpy(&u, &h, 2); return u;
}
static __device__ __forceinline__ float bff(u16 u) {
    __bf16 h; __builtin_memcpy(&h, &u, 2); return (float)h;
}
static __device__ __forceinline__ f32x4 MFMA(bf16x8 a, bf16x8 b, f32x4 c) {
    return __builtin_amdgcn_mfma_f32_16x16x32_bf16(a, b, c, 0, 0, 0);
}

// ---------------------------------------------------------------------------
__global__ __launch_bounds__(256) void zero_ws_kernel(float* __restrict__ p, int n) {
    int i = blockIdx.x * 256 + threadIdx.x;
    if (i < n) p[i] = 0.0f;
}

// ---------------------------------------------------------------------------
// Weight transform: w[oc=gate*128+cout][ch][kh][kw] -> 3 bf16 planes in
// fragment order: plane[((nt*6+ck)*9+tap)*512 + lane*8 + j],
// nt = cg*4+gate, lane = (kg<<4)|coutsub, ch = ck*32 + kg*8 + j.
__global__ __launch_bounds__(256) void wt_transform_kernel(
        const float* __restrict__ w, u16* __restrict__ wt) {
    int id = blockIdx.x * 256 + threadIdx.x;      // 110592
    int lane = id & 63;
    int rest = id >> 6;                            // 1728
    int tap = rest % 9;
    int rest2 = rest / 9;                          // 192
    int ck = rest2 % 6, nt = rest2 / 6;            // nt 0..31
    int gate = nt & 3, cg = nt >> 2;
    int coutsub = lane & 15, kgl = lane >> 4;
    int oc = gate * COUT + cg * 16 + coutsub;
    int kh = tap / 3, kw = tap - kh * 3;
    size_t dst = ((size_t)(nt * 6 + ck) * 9 + tap) * 512 + lane * 8;
#pragma unroll
    for (int j = 0; j < 8; ++j) {
        int ch = ck * 32 + kgl * 8 + j;
        float wv = w[((oc * 192 + ch) * 3 + kh) * 3 + kw];
        float hh = (float)(__bf16)wv;
        float r1 = wv - hh;
        float ll = (float)(__bf16)r1;
        float r2 = r1 - ll;
        wt[dst + j]            = bfbits(hh);
        wt[WTPL + dst + j]     = bfbits(ll);
        wt[2 * WTPL + dst + j] = bfbits(r2);
    }
}

// ---------------------------------------------------------------------------
// Alpha neuron; states ch-major f32 (float4); spk1 written pixel-major bf16.
__global__ __launch_bounds__(256) void alpha_step_kernel(
        const float4* __restrict__ x_t,
        const float* __restrict__ p_alpha, const float* __restrict__ p_beta,
        const float* __restrict__ p_th1,
        float4* __restrict__ syn_e, float4* __restrict__ syn_i,
        u16* __restrict__ spk1h) {
#pragma clang fp contract(off)
    int q = blockIdx.x * 256 + threadIdx.x;       // 294912 quads
    float a = fminf(fmaxf(p_alpha[0], 1e-6f), 1.0f - 1e-6f);
    float b = fminf(fmaxf(p_beta[0],  1e-6f), 1.0f - 1e-6f);
    float la = logf(a), lb = logf(b);
    float tau = la / (lb - la);
    float th1 = p_th1[0];

    int bc = q / 576;                              // b*64 + c
    int hw0 = (q - bc * 576) * 4;
    int bb = bc >> 6, c = bc & 63;
    u16* sp = spk1h + ((size_t)bb * HW + hw0) * 64 + c;

    float4 xv = x_t[q], e4 = syn_e[q], i4 = syn_i[q];
    float pr0 = bff(sp[0]), pr1 = bff(sp[64]), pr2 = bff(sp[128]), pr3 = bff(sp[192]);
    float e, ii, m1;
    u16 s0, s1, s2, s3;
    e = a * e4.x + xv.x; ii = b * i4.x - xv.x; m1 = tau * (e + ii) - pr0 * th1;
    e4.x = e; i4.x = ii; s0 = (m1 - th1) > 0.0f ? 0x3F80u : 0u;
    e = a * e4.y + xv.y; ii = b * i4.y - xv.y; m1 = tau * (e + ii) - pr1 * th1;
    e4.y = e; i4.y = ii; s1 = (m1 - th1) > 0.0f ? 0x3F80u : 0u;
    e = a * e4.z + xv.z; ii = b * i4.z - xv.z; m1 = tau * (e + ii) - pr2 * th1;
    e4.z = e; i4.z = ii; s2 = (m1 - th1) > 0.0f ? 0x3F80u : 0u;
    e = a * e4.w + xv.w; ii = b * i4.w - xv.w; m1 = tau * (e + ii) - pr3 * th1;
    e4.w = e; i4.w = ii; s3 = (m1 - th1) > 0.0f ? 0x3F80u : 0u;
    syn_e[q] = e4; syn_i[q] = i4;
    sp[0] = s0; sp[64] = s1; sp[128] = s2; sp[192] = s3;
}

// ---------------------------------------------------------------------------
// t=0: conv(all-zero input) = bias -> per-channel LSTM values.
__global__ void t0_u_kernel(const float* __restrict__ b_conv, float* __restrict__ u) {
#pragma clang fp contract(off)
    int c = threadIdx.x;                           // 128
    float gi = b_conv[c], gf = b_conv[COUT + c];
    float gg = b_conv[2 * COUT + c], go = b_conv[3 * COUT + c];
    float si = 1.0f / (1.0f + expf(-gi));
    float sf = 1.0f / (1.0f + expf(-gf));
    float so = 1.0f / (1.0f + expf(-go));
    float tg = tanhf(gg);
    float s2 = sf * 0.0f + si * tg;
    float m2 = so * tanhf(s2);
    u[c] = s2;
    u16* uh = (u16*)(u + 128);
    float hh = (float)(__bf16)m2;
    float r1 = m2 - hh;
    float ll = (float)(__bf16)r1;
    float r2 = r1 - ll;
    uh[c] = bfbits(hh); uh[128 + c] = bfbits(ll); uh[256 + c] = bfbits(r2);
}

// t=0 fill (ch-major): syn2 = u_s2[c], out(t0) = bn_beta[c].
__global__ __launch_bounds__(256) void t0_fillA_kernel(
        const float* __restrict__ u, const float* __restrict__ bnb,
        float4* __restrict__ syn2, float4* __restrict__ out0) {
    int i = blockIdx.x * 256 + threadIdx.x;        // 589824 quads
    int c = ((i * 4) / HW) % COUT;
    float s2 = u[c], bb = bnb[c];
    syn2[i] = make_float4(s2, s2, s2, s2);
    out0[i] = make_float4(bb, bb, bb, bb);
}

// t=0 fill (pixel-major): mem2 split planes.
__global__ __launch_bounds__(256) void t0_fillB_kernel(
        const float* __restrict__ u,
        u16* __restrict__ mh, u16* __restrict__ ml, u16* __restrict__ ml2) {
    int i = blockIdx.x * 256 + threadIdx.x;        // 589824
    int pg = i >> 5, c0 = (i & 31) * 4;
    const u16* uh = (const u16*)(u + 128);
    uint2 vh  = *(const uint2*)(uh + c0);
    uint2 vl  = *(const uint2*)(uh + 128 + c0);
    uint2 vl2 = *(const uint2*)(uh + 256 + c0);
    *(uint2*)(mh  + (size_t)pg * 128 + c0) = vh;
    *(uint2*)(ml  + (size_t)pg * 128 + c0) = vl;
    *(uint2*)(ml2 + (size_t)pg * 128 + c0) = vl2;
}

// ---------------------------------------------------------------------------
// MFMA conv. Block: 4 waves, each wave = ONE nt (N=16), M=64 px.
// Grid 2304: ntq = bx&7 (XCD weight-slice affinity), mtb = bx>>3 = b*36+mt.
__global__ __launch_bounds__(256, 4) void conv_mfma(
        const u16* __restrict__ spk1h,
        const u16* __restrict__ m2h, const u16* __restrict__ m2l,
        const u16* __restrict__ m2l2,
        const u16* __restrict__ wt,
        float* __restrict__ cc) {
    __shared__ u16 alds[3][4320];                  // [plane][6 rows][18 cols][40 ch]

    const int bx  = blockIdx.x;
    const int ntq = bx & 7;
    const int mtb = bx >> 3;                       // 0..287
    const int b   = mtb / 36;
    const int mt  = mtb - b * 36;
    const int mt3 = mt / 3;
    const int h0 = mt3 * 4, w0 = (mt - mt3 * 3) * 16;

    const int tid = threadIdx.x;
    const int wn  = tid >> 6;
    const int lane = tid & 63;
    const int m16 = lane & 15;
    const int kg  = lane >> 4;
    const size_t pxbase = (size_t)b * HW;
    const int nt = ntq * 4 + wn;

    f32x4 acc[4];
#pragma unroll
    for (int mf = 0; mf < 4; ++mf) acc[mf] = (f32x4){0.f, 0.f, 0.f, 0.f};

    // ---------------- binary chunks (spk1, ck 0..1): 3-term ----------------
    for (int ck = 0; ck < 2; ++ck) {
        __syncthreads();
        {
            const u16* s0 = spk1h + pxbase * 64 + ck * 32;
            for (int i = tid; i < 432; i += 256) {
                int px = i >> 2, qt = i & 3;
                int rr = px / 18, ccx = px - rr * 18;
                int gh = h0 - 1 + rr, gw = w0 - 1 + ccx;
                uint4 v = make_uint4(0u, 0u, 0u, 0u);
                if ((unsigned)gh < 48u && (unsigned)gw < 48u)
                    v = *(const uint4*)(s0 + (size_t)(gh * 48 + gw) * 64 + qt * 8);
                *(uint4*)&alds[0][px * 40 + qt * 8] = v;
            }
        }
        __syncthreads();
#pragma unroll
        for (int kh = 0; kh < 3; ++kh)
#pragma unroll
        for (int kw = 0; kw < 3; ++kw) {
            bf16x8 Ah[4];
#pragma unroll
            for (int mf = 0; mf < 4; ++mf)
                Ah[mf] = *(const bf16x8*)&alds[0][((mf + kh) * 18 + m16 + kw) * 40 + kg * 8];
            const size_t bo = ((size_t)(nt * 6 + ck) * 9 + (kh * 3 + kw)) * 512 + lane * 8;
            bf16x8 Bh  = *(const bf16x8*)(wt + bo);
            bf16x8 Bl  = *(const bf16x8*)(wt + WTPL + bo);
            bf16x8 Bl2 = *(const bf16x8*)(wt + 2 * WTPL + bo);
#pragma unroll
            for (int mf = 0; mf < 4; ++mf) acc[mf] = MFMA(Ah[mf], Bh,  acc[mf]);
#pragma unroll
            for (int mf = 0; mf < 4; ++mf) acc[mf] = MFMA(Ah[mf], Bl,  acc[mf]);
#pragma unroll
            for (int mf = 0; mf < 4; ++mf) acc[mf] = MFMA(Ah[mf], Bl2, acc[mf]);
        }
    }

    // ---------------- mem2 chunks (ck 2..5): 7-term ----------------
    for (int ck = 2; ck < 6; ++ck) {
        __syncthreads();
        {
            const int ch0 = (ck - 2) * 32;
            const u16* s0 = m2h  + pxbase * 128 + ch0;
            const u16* s1 = m2l  + pxbase * 128 + ch0;
            const u16* s2 = m2l2 + pxbase * 128 + ch0;
            for (int i = tid; i < 1296; i += 256) {
                int pl = i / 432;
                int r = i - pl * 432;
                int px = r >> 2, qt = r & 3;
                int rr = px / 18, ccx = px - rr * 18;
                int gh = h0 - 1 + rr, gw = w0 - 1 + ccx;
                uint4 v = make_uint4(0u, 0u, 0u, 0u);
                if ((unsigned)gh < 48u && (unsigned)gw < 48u) {
                    const u16* sp = (pl == 0 ? s0 : (pl == 1 ? s1 : s2));
                    v = *(const uint4*)(sp + (size_t)(gh * 48 + gw) * 128 + qt * 8);
                }
                *(uint4*)&alds[pl][px * 40 + qt * 8] = v;
            }
        }
        __syncthreads();
#pragma unroll
        for (int kh = 0; kh < 3; ++kh)
#pragma unroll
        for (int kw = 0; kw < 3; ++kw) {
            bf16x8 Ah[4], Al[4], Al2[4];
#pragma unroll
            for (int mf = 0; mf < 4; ++mf) {
                const int ai = ((mf + kh) * 18 + m16 + kw) * 40 + kg * 8;
                Ah[mf]  = *(const bf16x8*)&alds[0][ai];
                Al[mf]  = *(const bf16x8*)&alds[1][ai];
                Al2[mf] = *(const bf16x8*)&alds[2][ai];
            }
            const size_t bo = ((size_t)(nt * 6 + ck) * 9 + (kh * 3 + kw)) * 512 + lane * 8;
            bf16x8 Bh  = *(const bf16x8*)(wt + bo);
            bf16x8 Bl  = *(const bf16x8*)(wt + WTPL + bo);
            bf16x8 Bl2 = *(const bf16x8*)(wt + 2 * WTPL + bo);
#pragma unroll
            for (int mf = 0; mf < 4; ++mf) acc[mf] = MFMA(Ah[mf],  Bh,  acc[mf]);
#pragma unroll
            for (int mf = 0; mf < 4; ++mf) acc[mf] = MFMA(Ah[mf],  Bl,  acc[mf]);
#pragma unroll
            for (int mf = 0; mf < 4; ++mf) acc[mf] = MFMA(Ah[mf],  Bl2, acc[mf]);
#pragma unroll
            for (int mf = 0; mf < 4; ++mf) acc[mf] = MFMA(Al[mf],  Bh,  acc[mf]);
#pragma unroll
            for (int mf = 0; mf < 4; ++mf) acc[mf] = MFMA(Al[mf],  Bl,  acc[mf]);
#pragma unroll
            for (int mf = 0; mf < 4; ++mf) acc[mf] = MFMA(Al2[mf], Bh,  acc[mf]);
#pragma unroll
            for (int mf = 0; mf < 4; ++mf) acc[mf] = MFMA(Al2[mf], Bl,  acc[mf]);
        }
    }

    // ---- store raw gate sums: cc[b][nt*16+m16][h0+mf][w0+kg*4 .. +3] ----
#pragma unroll
    for (int mf = 0; mf < 4; ++mf) {
        float* dst = cc + ((size_t)(b * 512 + nt * 16 + m16) * HW
                           + (size_t)(h0 + mf) * 48 + w0 + kg * 4);
        *(f32x4*)dst = acc[mf];
    }
}

// ---------------------------------------------------------------------------
// LSTM elementwise: reads cc (+bias), updates syn2, writes m2 h/l/l2 planes,
// spk2h, and exact per-channel spike counts. Thread = (b, cout, 4 px).
__global__ __launch_bounds__(256) void lstm_step_kernel(
        const float* __restrict__ cc, const float* __restrict__ bias,
        const float* __restrict__ p_th2,
        float* __restrict__ syn2,
        u16* __restrict__ m2h, u16* __restrict__ m2l, u16* __restrict__ m2l2,
        u16* __restrict__ spk2h, int* __restrict__ cnt) {
#pragma clang fp contract(off)
    int i = blockIdx.x * 256 + threadIdx.x;        // 589824
    int bc = i / 576;
    int px0 = (i - bc * 576) * 4;
    int b = bc >> 7, c = bc & 127;
    int cg = c >> 4, cs = c & 15;
    const int lane = threadIdx.x & 63;
    const float th2 = p_th2[0];
    const float b0 = bias[c],       b1 = bias[128 + c];
    const float b2 = bias[256 + c], b3 = bias[384 + c];
    // gate g lives at cc channel (cg*4+g)*16 + cs = cg*64 + g*16 + cs
    const size_t gbase = ((size_t)b * 512 + (size_t)cg * 64 + cs) * HW + px0;
    const float4 vI = *(const float4*)(cc + gbase);
    const float4 vF = *(const float4*)(cc + gbase + (size_t)16 * HW);
    const float4 vG = *(const float4*)(cc + gbase + (size_t)32 * HW);
    const float4 vO = *(const float4*)(cc + gbase + (size_t)48 * HW);
    const size_t sidx = ((size_t)b * 128 + c) * HW + px0;
    const float4 s2v = *(const float4*)(syn2 + sidx);
    const float aI[4] = {vI.x, vI.y, vI.z, vI.w};
    const float aF[4] = {vF.x, vF.y, vF.z, vF.w};
    const float aG[4] = {vG.x, vG.y, vG.z, vG.w};
    const float aO[4] = {vO.x, vO.y, vO.z, vO.w};
    const float aS[4] = {s2v.x, s2v.y, s2v.z, s2v.w};
    float s2o[4];
    int sc = 0;
#pragma unroll
    for (int j = 0; j < 4; ++j) {
        float gi = aI[j] + b0, gf = aF[j] + b1;
        float gg = aG[j] + b2, go = aO[j] + b3;
        float si = 1.0f / (1.0f + expf(-gi));
        float sf = 1.0f / (1.0f + expf(-gf));
        float so = 1.0f / (1.0f + expf(-go));
        float tg = tanhf(gg);
        float s2 = sf * aS[j] + si * tg;
        float m2 = so * tanhf(s2);
        s2o[j] = s2;
        float hh = (float)(__bf16)m2;
        float r1 = m2 - hh;
        float ll = (float)(__bf16)r1;
        float r2 = r1 - ll;
        const size_t pix = ((size_t)b * HW + px0 + j) * 128 + c;
        m2h[pix]  = bfbits(hh);
        m2l[pix]  = bfbits(ll);
        m2l2[pix] = bfbits(r2);
        bool sp = (m2 - th2) > 0.0f;
        spk2h[pix] = sp ? 0x3F80u : 0u;
        sc += sp ? 1 : 0;
    }
    *(float4*)(syn2 + sidx) = make_float4(s2o[0], s2o[1], s2o[2], s2o[3]);
    // wave spans 64 consecutive px4-groups of the SAME (b,c): 576 % 64 == 0
    sc += __shfl_xor(sc, 1);  sc += __shfl_xor(sc, 2);  sc += __shfl_xor(sc, 4);
    sc += __shfl_xor(sc, 8);  sc += __shfl_xor(sc, 16); sc += __shfl_xor(sc, 32);
    if (lane == 0) atomicAdd(&cnt[c], sc);
}

// ---------------------------------------------------------------------------
// BN of binary spikes: mu = cnt/NPIX exact, var = mu - mu^2; reads pm bf16.
__global__ __launch_bounds__(256) void bn_step_kernel(
        const u16* __restrict__ spk2h, const int* __restrict__ cnt,
        const float* __restrict__ gamma, const float* __restrict__ bnb,
        float4* __restrict__ out) {
#pragma clang fp contract(off)
    int i = blockIdx.x * 256 + threadIdx.x;        // 589824 quads (ch-major out)
    int e = i * 4;
    int tmp = e / HW;                               // b*128 + c
    int bb = tmp >> 7, c = tmp & 127;
    int hw0 = e - tmp * HW;
    const u16* sp = spk2h + ((size_t)bb * HW + hw0) * 128 + c;
    float mu  = (float)cnt[c] / (float)NPIX;
    float var = mu - mu * mu;
    float rs  = rsqrtf(var + 1e-5f);
    float g = gamma[c], bv = bnb[c];
    float s0 = bff(sp[0]), s1 = bff(sp[128]), s2 = bff(sp[256]), s3 = bff(sp[384]);
    out[i] = make_float4(g * (s0 - mu) * rs + bv, g * (s1 - mu) * rs + bv,
                         g * (s2 - mu) * rs + bv, g * (s3 - mu) * rs + bv);
}

// ---------------------------------------------------------------------------
extern "C" void kernel_launch(void* const* d_in, const int* in_sizes, int n_in,
                              void* d_out, int out_size, void* d_ws, size_t ws_size,
                              hipStream_t stream) {
    const float* x       = (const float*)d_in[0];
    const float* p_alpha = (const float*)d_in[1];
    const float* p_beta  = (const float*)d_in[2];
    const float* p_th1   = (const float*)d_in[3];
    const float* p_th2   = (const float*)d_in[4];
    const float* w_conv  = (const float*)d_in[5];
    const float* b_conv  = (const float*)d_in[6];
    const float* gamma   = (const float*)d_in[7];
    const float* bn_beta = (const float*)d_in[8];
    float* out = (float*)d_out;

    float* wsf   = (float*)d_ws;
    float* syn_e = wsf + OFF_SYNE;
    float* syn_i = wsf + OFF_SYNI;
    u16*   spk1h = (u16*)(wsf + OFF_SPK1H);
    int*   cnt   = (int*)(wsf + OFF_CNT);
    float* syn2  = wsf + OFF_SYN2;
    u16*   spk2h = (u16*)(wsf + OFF_SPK2H);
    u16*   m2h   = (u16*)(wsf + OFF_M2H);
    u16*   m2l   = (u16*)(wsf + OFF_M2L);
    u16*   m2l2  = (u16*)(wsf + OFF_M2L2);
    u16*   wt    = (u16*)(wsf + OFF_WT);
    float* u     = wsf + OFF_U;
    float* cc    = wsf + OFF_CC;

    zero_ws_kernel<<<ZERO_W / 256, 256, 0, stream>>>(wsf, ZERO_W);
    wt_transform_kernel<<<432, 256, 0, stream>>>(w_conv, wt);

    // ---- t = 0 (algebraic) ----
    alpha_step_kernel<<<1152, 256, 0, stream>>>(
        (const float4*)x, p_alpha, p_beta, p_th1,
        (float4*)syn_e, (float4*)syn_i, spk1h);
    t0_u_kernel<<<1, COUT, 0, stream>>>(b_conv, u);
    t0_fillA_kernel<<<2304, 256, 0, stream>>>(
        u, bn_beta, (float4*)syn2, (float4*)out);
    t0_fillB_kernel<<<2304, 256, 0, stream>>>(u, m2h, m2l, m2l2);

    // ---- t = 1..3 ----
    for (int t = 1; t < T_; ++t) {
        alpha_step_kernel<<<1152, 256, 0, stream>>>(
            (const float4*)(x + (size_t)t * 1179648), p_alpha, p_beta, p_th1,
            (float4*)syn_e, (float4*)syn_i, spk1h);
        conv_mfma<<<2304, 256, 0, stream>>>(
            spk1h, m2h, m2l, m2l2, wt, cc);
        lstm_step_kernel<<<2304, 256, 0, stream>>>(
            cc, b_conv, p_th2, syn2, m2h, m2l, m2l2, spk2h, cnt + t * COUT);
        bn_step_kernel<<<2304, 256, 0, stream>>>(
            spk2h, cnt + t * COUT, gamma, bn_beta,
            (float4*)(out + (size_t)t * 2359296));
    }
}

// Round 9
// 839.171 us; speedup vs baseline: 3.1409x; 1.1329x over previous
//
#include <hip/hip_runtime.h>

// ---------------------------------------------------------------------------
// snnBlock, round 9: MFMA conv (verified r7/r8 core) with traffic fixes:
//  * grid: bx = ntq*288 + mt*8 + b  -> XCD = b (A-set L2-resident per XCD,
//    wt slice streams per ntq phase)
//  * cc in fragment-native layout [bmt][nt][mf][lane][reg]: wave stores 4KB
//    contiguous (no partial-line RMW)
//  * lstm_step in fragment coordinates: per-gate 1KB contiguous wave reads;
//    syn2 in fragment layout; coalesced m2/spk2 writes
// ---------------------------------------------------------------------------

typedef unsigned short u16;
typedef __attribute__((ext_vector_type(8))) __bf16 bf16x8;
typedef __attribute__((ext_vector_type(4))) float   f32x4;

#define T_ 4
#define B_ 8
#define CIN 64
#define COUT 128
#define H_ 48
#define W_ 48
#define HW 2304
#define NPIX 18432
#define KTOT 1728
#define WTPL 884736            // elements per weight plane

// ---- workspace layout (32-bit words) ----
#define OFF_SYNE  0
#define OFF_SYNI  1179648
#define OFF_SPK1H 2359296      // bf16 [B][HW][64]
#define OFF_CNT   2949120      // int [T][128]
#define ZERO_W    2949632
#define OFF_SYN2  2949632      // f32 fragment layout [bmt][cg][mf][lane][reg]
#define OFF_SPK2H 5308928      // bf16 [B][HW][128]
#define OFF_M2H   6488576      // bf16 [B][HW][128]
#define OFF_M2L   7078400
#define OFF_M2L2  7668224
#define OFF_WT    8258048      // bf16 [3][884736]
#define OFF_U     9585152      // f32 us2[128]; u16 uh/ul/ul2[3][128]
#define OFF_CC    9585664      // f32 fragment layout [bmt][nt][mf][lane][reg]

static __device__ __forceinline__ u16 bfbits(float f) {
    __bf16 h = (__bf16)f; u16 u; __builtin_memcpy(&u, &h, 2); return u;
}
static __device__ __forceinline__ float bff(u16 u) {
    __bf16 h; __builtin_memcpy(&h, &u, 2); return (float)h;
}
static __device__ __forceinline__ f32x4 MFMA(bf16x8 a, bf16x8 b, f32x4 c) {
    return __builtin_amdgcn_mfma_f32_16x16x32_bf16(a, b, c, 0, 0, 0);
}

// ---------------------------------------------------------------------------
__global__ __launch_bounds__(256) void zero_ws_kernel(float* __restrict__ p, int n) {
    int i = blockIdx.x * 256 + threadIdx.x;
    if (i < n) p[i] = 0.0f;
}

// ---------------------------------------------------------------------------
// Weight transform (unchanged, r7-verified): 3 bf16 planes in fragment order.
__global__ __launch_bounds__(256) void wt_transform_kernel(
        const float* __restrict__ w, u16* __restrict__ wt) {
    int id = blockIdx.x * 256 + threadIdx.x;      // 110592
    int lane = id & 63;
    int rest = id >> 6;                            // 1728
    int tap = rest % 9;
    int rest2 = rest / 9;                          // 192
    int ck = rest2 % 6, nt = rest2 / 6;            // nt 0..31
    int gate = nt & 3, cg = nt >> 2;
    int coutsub = lane & 15, kgl = lane >> 4;
    int oc = gate * COUT + cg * 16 + coutsub;
    int kh = tap / 3, kw = tap - kh * 3;
    size_t dst = ((size_t)(nt * 6 + ck) * 9 + tap) * 512 + lane * 8;
#pragma unroll
    for (int j = 0; j < 8; ++j) {
        int ch = ck * 32 + kgl * 8 + j;
        float wv = w[((oc * 192 + ch) * 3 + kh) * 3 + kw];
        float hh = (float)(__bf16)wv;
        float r1 = wv - hh;
        float ll = (float)(__bf16)r1;
        float r2 = r1 - ll;
        wt[dst + j]            = bfbits(hh);
        wt[WTPL + dst + j]     = bfbits(ll);
        wt[2 * WTPL + dst + j] = bfbits(r2);
    }
}

// ---------------------------------------------------------------------------
// Alpha neuron (unchanged).
__global__ __launch_bounds__(256) void alpha_step_kernel(
        const float4* __restrict__ x_t,
        const float* __restrict__ p_alpha, const float* __restrict__ p_beta,
        const float* __restrict__ p_th1,
        float4* __restrict__ syn_e, float4* __restrict__ syn_i,
        u16* __restrict__ spk1h) {
#pragma clang fp contract(off)
    int q = blockIdx.x * 256 + threadIdx.x;       // 294912 quads
    float a = fminf(fmaxf(p_alpha[0], 1e-6f), 1.0f - 1e-6f);
    float b = fminf(fmaxf(p_beta[0],  1e-6f), 1.0f - 1e-6f);
    float la = logf(a), lb = logf(b);
    float tau = la / (lb - la);
    float th1 = p_th1[0];

    int bc = q / 576;                              // b*64 + c
    int hw0 = (q - bc * 576) * 4;
    int bb = bc >> 6, c = bc & 63;
    u16* sp = spk1h + ((size_t)bb * HW + hw0) * 64 + c;

    float4 xv = x_t[q], e4 = syn_e[q], i4 = syn_i[q];
    float pr0 = bff(sp[0]), pr1 = bff(sp[64]), pr2 = bff(sp[128]), pr3 = bff(sp[192]);
    float e, ii, m1;
    u16 s0, s1, s2, s3;
    e = a * e4.x + xv.x; ii = b * i4.x - xv.x; m1 = tau * (e + ii) - pr0 * th1;
    e4.x = e; i4.x = ii; s0 = (m1 - th1) > 0.0f ? 0x3F80u : 0u;
    e = a * e4.y + xv.y; ii = b * i4.y - xv.y; m1 = tau * (e + ii) - pr1 * th1;
    e4.y = e; i4.y = ii; s1 = (m1 - th1) > 0.0f ? 0x3F80u : 0u;
    e = a * e4.z + xv.z; ii = b * i4.z - xv.z; m1 = tau * (e + ii) - pr2 * th1;
    e4.z = e; i4.z = ii; s2 = (m1 - th1) > 0.0f ? 0x3F80u : 0u;
    e = a * e4.w + xv.w; ii = b * i4.w - xv.w; m1 = tau * (e + ii) - pr3 * th1;
    e4.w = e; i4.w = ii; s3 = (m1 - th1) > 0.0f ? 0x3F80u : 0u;
    syn_e[q] = e4; syn_i[q] = i4;
    sp[0] = s0; sp[64] = s1; sp[128] = s2; sp[192] = s3;
}

// ---------------------------------------------------------------------------
// t=0: conv(all-zero input) = bias -> per-channel LSTM values.
__global__ void t0_u_kernel(const float* __restrict__ b_conv, float* __restrict__ u) {
#pragma clang fp contract(off)
    int c = threadIdx.x;                           // 128
    float gi = b_conv[c], gf = b_conv[COUT + c];
    float gg = b_conv[2 * COUT + c], go = b_conv[3 * COUT + c];
    float si = 1.0f / (1.0f + expf(-gi));
    float sf = 1.0f / (1.0f + expf(-gf));
    float so = 1.0f / (1.0f + expf(-go));
    float tg = tanhf(gg);
    float s2 = sf * 0.0f + si * tg;
    float m2 = so * tanhf(s2);
    u[c] = s2;
    u16* uh = (u16*)(u + 128);
    float hh = (float)(__bf16)m2;
    float r1 = m2 - hh;
    float ll = (float)(__bf16)r1;
    float r2 = r1 - ll;
    uh[c] = bfbits(hh); uh[128 + c] = bfbits(ll); uh[256 + c] = bfbits(r2);
}

// t=0 fill A: out(t0) = bn_beta[c] (ch-major, matches output layout).
__global__ __launch_bounds__(256) void t0_fillA_kernel(
        const float* __restrict__ u, const float* __restrict__ bnb,
        float4* __restrict__ out0) {
    int i = blockIdx.x * 256 + threadIdx.x;        // 589824 quads
    int c = ((i * 4) / HW) % COUT;
    float bb = bnb[c];
    out0[i] = make_float4(bb, bb, bb, bb);
}

// t=0 fill B: m2 planes (pixel-major) + syn2 (fragment layout).
__global__ __launch_bounds__(256) void t0_fillB_kernel(
        const float* __restrict__ u,
        u16* __restrict__ mh, u16* __restrict__ ml, u16* __restrict__ ml2,
        float4* __restrict__ syn2) {
    int i = blockIdx.x * 256 + threadIdx.x;        // 589824
    {   // m2 planes: 4 channels of one pixel
        int pg = i >> 5, c0 = (i & 31) * 4;
        const u16* uh = (const u16*)(u + 128);
        uint2 vh  = *(const uint2*)(uh + c0);
        uint2 vl  = *(const uint2*)(uh + 128 + c0);
        uint2 vl2 = *(const uint2*)(uh + 256 + c0);
        *(uint2*)(mh  + (size_t)pg * 128 + c0) = vh;
        *(uint2*)(ml  + (size_t)pg * 128 + c0) = vl;
        *(uint2*)(ml2 + (size_t)pg * 128 + c0) = vl2;
    }
    {   // syn2 fragment layout: word f = i*4+reg -> c = ((i>>8)&7)*16 + (i&15)
        int c = ((i >> 8) & 7) * 16 + (i & 15);
        float s2 = u[c];
        syn2[i] = make_float4(s2, s2, s2, s2);
    }
}

// ---------------------------------------------------------------------------
// MFMA conv. Block: 4 waves, each wave ONE nt (N=16), M=64 px.
// Grid 2304: bx = ntq*288 + mt*8 + b  ->  XCD = bx%8 = b.
// cc fragment layout: cc[((bmt*32 + nt)*4 + mf)*256 + lane*4 + reg].
__global__ __launch_bounds__(256, 4) void conv_mfma(
        const u16* __restrict__ spk1h,
        const u16* __restrict__ m2h, const u16* __restrict__ m2l,
        const u16* __restrict__ m2l2,
        const u16* __restrict__ wt,
        float* __restrict__ cc) {
    __shared__ u16 alds[3][4320];                  // [plane][6 rows][18 cols][40 ch]

    const int bx  = blockIdx.x;
    const int ntq = bx / 288;
    const int rm  = bx - ntq * 288;                // mt*8 + b
    const int mt  = rm >> 3;
    const int b   = rm & 7;
    const int mt3 = mt / 3;
    const int h0 = mt3 * 4, w0 = (mt - mt3 * 3) * 16;

    const int tid = threadIdx.x;
    const int wn  = tid >> 6;
    const int lane = tid & 63;
    const int m16 = lane & 15;
    const int kg  = lane >> 4;
    const size_t pxbase = (size_t)b * HW;
    const int nt = ntq * 4 + wn;

    f32x4 acc[4];
#pragma unroll
    for (int mf = 0; mf < 4; ++mf) acc[mf] = (f32x4){0.f, 0.f, 0.f, 0.f};

    // ---------------- binary chunks (spk1, ck 0..1): 3-term ----------------
    for (int ck = 0; ck < 2; ++ck) {
        __syncthreads();
        {
            const u16* s0 = spk1h + pxbase * 64 + ck * 32;
            for (int i = tid; i < 432; i += 256) {
                int px = i >> 2, qt = i & 3;
                int rr = px / 18, ccx = px - rr * 18;
                int gh = h0 - 1 + rr, gw = w0 - 1 + ccx;
                uint4 v = make_uint4(0u, 0u, 0u, 0u);
                if ((unsigned)gh < 48u && (unsigned)gw < 48u)
                    v = *(const uint4*)(s0 + (size_t)(gh * 48 + gw) * 64 + qt * 8);
                *(uint4*)&alds[0][px * 40 + qt * 8] = v;
            }
        }
        __syncthreads();
#pragma unroll
        for (int kh = 0; kh < 3; ++kh)
#pragma unroll
        for (int kw = 0; kw < 3; ++kw) {
            bf16x8 Ah[4];
#pragma unroll
            for (int mf = 0; mf < 4; ++mf)
                Ah[mf] = *(const bf16x8*)&alds[0][((mf + kh) * 18 + m16 + kw) * 40 + kg * 8];
            const size_t bo = ((size_t)(nt * 6 + ck) * 9 + (kh * 3 + kw)) * 512 + lane * 8;
            bf16x8 Bh  = *(const bf16x8*)(wt + bo);
            bf16x8 Bl  = *(const bf16x8*)(wt + WTPL + bo);
            bf16x8 Bl2 = *(const bf16x8*)(wt + 2 * WTPL + bo);
#pragma unroll
            for (int mf = 0; mf < 4; ++mf) acc[mf] = MFMA(Ah[mf], Bh,  acc[mf]);
#pragma unroll
            for (int mf = 0; mf < 4; ++mf) acc[mf] = MFMA(Ah[mf], Bl,  acc[mf]);
#pragma unroll
            for (int mf = 0; mf < 4; ++mf) acc[mf] = MFMA(Ah[mf], Bl2, acc[mf]);
        }
    }

    // ---------------- mem2 chunks (ck 2..5): 7-term ----------------
    for (int ck = 2; ck < 6; ++ck) {
        __syncthreads();
        {
            const int ch0 = (ck - 2) * 32;
            const u16* s0 = m2h  + pxbase * 128 + ch0;
            const u16* s1 = m2l  + pxbase * 128 + ch0;
            const u16* s2 = m2l2 + pxbase * 128 + ch0;
            for (int i = tid; i < 1296; i += 256) {
                int pl = i / 432;
                int r = i - pl * 432;
                int px = r >> 2, qt = r & 3;
                int rr = px / 18, ccx = px - rr * 18;
                int gh = h0 - 1 + rr, gw = w0 - 1 + ccx;
                uint4 v = make_uint4(0u, 0u, 0u, 0u);
                if ((unsigned)gh < 48u && (unsigned)gw < 48u) {
                    const u16* sp = (pl == 0 ? s0 : (pl == 1 ? s1 : s2));
                    v = *(const uint4*)(sp + (size_t)(gh * 48 + gw) * 128 + qt * 8);
                }
                *(uint4*)&alds[pl][px * 40 + qt * 8] = v;
            }
        }
        __syncthreads();
#pragma unroll
        for (int kh = 0; kh < 3; ++kh)
#pragma unroll
        for (int kw = 0; kw < 3; ++kw) {
            bf16x8 Ah[4], Al[4], Al2[4];
#pragma unroll
            for (int mf = 0; mf < 4; ++mf) {
                const int ai = ((mf + kh) * 18 + m16 + kw) * 40 + kg * 8;
                Ah[mf]  = *(const bf16x8*)&alds[0][ai];
                Al[mf]  = *(const bf16x8*)&alds[1][ai];
                Al2[mf] = *(const bf16x8*)&alds[2][ai];
            }
            const size_t bo = ((size_t)(nt * 6 + ck) * 9 + (kh * 3 + kw)) * 512 + lane * 8;
            bf16x8 Bh  = *(const bf16x8*)(wt + bo);
            bf16x8 Bl  = *(const bf16x8*)(wt + WTPL + bo);
            bf16x8 Bl2 = *(const bf16x8*)(wt + 2 * WTPL + bo);
#pragma unroll
            for (int mf = 0; mf < 4; ++mf) acc[mf] = MFMA(Ah[mf],  Bh,  acc[mf]);
#pragma unroll
            for (int mf = 0; mf < 4; ++mf) acc[mf] = MFMA(Ah[mf],  Bl,  acc[mf]);
#pragma unroll
            for (int mf = 0; mf < 4; ++mf) acc[mf] = MFMA(Ah[mf],  Bl2, acc[mf]);
#pragma unroll
            for (int mf = 0; mf < 4; ++mf) acc[mf] = MFMA(Al[mf],  Bh,  acc[mf]);
#pragma unroll
            for (int mf = 0; mf < 4; ++mf) acc[mf] = MFMA(Al[mf],  Bl,  acc[mf]);
#pragma unroll
            for (int mf = 0; mf < 4; ++mf) acc[mf] = MFMA(Al2[mf], Bh,  acc[mf]);
#pragma unroll
            for (int mf = 0; mf < 4; ++mf) acc[mf] = MFMA(Al2[mf], Bl,  acc[mf]);
        }
    }

    // ---- store raw gate sums, fragment-native (4KB contiguous per wave) ----
    const size_t cbase = ((size_t)((b * 36 + mt) * 32 + nt) * 4) * 256;
#pragma unroll
    for (int mf = 0; mf < 4; ++mf)
        *(f32x4*)(cc + cbase + mf * 256 + lane * 4) = acc[mf];
}

// ---------------------------------------------------------------------------
// LSTM in fragment coordinates. Wave = (b, mt, cg, mf); lane = kg*16+m16.
// Thread: channel c = cg*16+m16, pixels w-cols kg*4+0..3 of row h.
__global__ __launch_bounds__(256) void lstm_step_kernel(
        const float* __restrict__ cc, const float* __restrict__ bias,
        const float* __restrict__ p_th2,
        float* __restrict__ syn2,
        u16* __restrict__ m2h, u16* __restrict__ m2l, u16* __restrict__ m2l2,
        u16* __restrict__ spk2h, int* __restrict__ cnt) {
#pragma clang fp contract(off)
    const int i = blockIdx.x * 256 + threadIdx.x;  // 589824
    const int lane = i & 63;
    const int w64 = i >> 6;                        // ((bmt*8+cg)*4+mf)
    const int mf = w64 & 3;
    const int cg = (w64 >> 2) & 7;
    const int bmt = w64 >> 5;                      // b*36 + mt
    const int b = bmt / 36;
    const int mt = bmt - b * 36;
    const int m16 = lane & 15, kg = lane >> 4;
    const int c = cg * 16 + m16;

    const size_t ccbase = ((size_t)(bmt * 32 + cg * 4) * 4 + mf) * 256 + lane * 4;
    const f32x4 vI = *(const f32x4*)(cc + ccbase);
    const f32x4 vF = *(const f32x4*)(cc + ccbase + 1024);
    const f32x4 vG = *(const f32x4*)(cc + ccbase + 2048);
    const f32x4 vO = *(const f32x4*)(cc + ccbase + 3072);
    const size_t sidx = (size_t)i * 4;             // syn2 fragment layout
    const f32x4 s2v = *(const f32x4*)(syn2 + sidx);

    const float th2 = p_th2[0];
    const float b0 = bias[c],       b1 = bias[128 + c];
    const float b2 = bias[256 + c], b3 = bias[384 + c];

    const int h = (mt / 3) * 4 + mf;
    const int wc0 = (mt % 3) * 16 + kg * 4;
    const size_t pixbase = ((size_t)b * HW + h * 48 + wc0) * 128 + c;

    f32x4 s2o;
    int sc = 0;
#pragma unroll
    for (int j = 0; j < 4; ++j) {
        float gi = vI[j] + b0, gf = vF[j] + b1;
        float gg = vG[j] + b2, go = vO[j] + b3;
        float si = 1.0f / (1.0f + expf(-gi));
        float sf = 1.0f / (1.0f + expf(-gf));
        float so = 1.0f / (1.0f + expf(-go));
        float tg = tanhf(gg);
        float s2 = sf * s2v[j] + si * tg;
        float m2 = so * tanhf(s2);
        s2o[j] = s2;
        float hh = (float)(__bf16)m2;
        float r1 = m2 - hh;
        float ll = (float)(__bf16)r1;
        float r2 = r1 - ll;
        const size_t pix = pixbase + (size_t)j * 128;
        m2h[pix]  = bfbits(hh);
        m2l[pix]  = bfbits(ll);
        m2l2[pix] = bfbits(r2);
        bool sp = (m2 - th2) > 0.0f;
        spk2h[pix] = sp ? 0x3F80u : 0u;
        sc += sp ? 1 : 0;
    }
    *(f32x4*)(syn2 + sidx) = s2o;
    // reduce over kg (lane bits 4,5): lanes<16 hold per-channel sums of 16 px
    sc += __shfl_xor(sc, 16);
    sc += __shfl_xor(sc, 32);
    if (lane < 16) atomicAdd(&cnt[c], sc);
}

// ---------------------------------------------------------------------------
// BN of binary spikes: mu = cnt/NPIX exact, var = mu - mu^2; reads pm bf16.
__global__ __launch_bounds__(256) void bn_step_kernel(
        const u16* __restrict__ spk2h, const int* __restrict__ cnt,
        const float* __restrict__ gamma, const float* __restrict__ bnb,
        float4* __restrict__ out) {
#pragma clang fp contract(off)
    int i = blockIdx.x * 256 + threadIdx.x;        // 589824 quads (ch-major out)
    int e = i * 4;
    int tmp = e / HW;                               // b*128 + c
    int bb = tmp >> 7, c = tmp & 127;
    int hw0 = e - tmp * HW;
    const u16* sp = spk2h + ((size_t)bb * HW + hw0) * 128 + c;
    float mu  = (float)cnt[c] / (float)NPIX;
    float var = mu - mu * mu;
    float rs  = rsqrtf(var + 1e-5f);
    float g = gamma[c], bv = bnb[c];
    float s0 = bff(sp[0]), s1 = bff(sp[128]), s2 = bff(sp[256]), s3 = bff(sp[384]);
    out[i] = make_float4(g * (s0 - mu) * rs + bv, g * (s1 - mu) * rs + bv,
                         g * (s2 - mu) * rs + bv, g * (s3 - mu) * rs + bv);
}

// ---------------------------------------------------------------------------
extern "C" void kernel_launch(void* const* d_in, const int* in_sizes, int n_in,
                              void* d_out, int out_size, void* d_ws, size_t ws_size,
                              hipStream_t stream) {
    const float* x       = (const float*)d_in[0];
    const float* p_alpha = (const float*)d_in[1];
    const float* p_beta  = (const float*)d_in[2];
    const float* p_th1   = (const float*)d_in[3];
    const float* p_th2   = (const float*)d_in[4];
    const float* w_conv  = (const float*)d_in[5];
    const float* b_conv  = (const float*)d_in[6];
    const float* gamma   = (const float*)d_in[7];
    const float* bn_beta = (const float*)d_in[8];
    float* out = (float*)d_out;

    float* wsf   = (float*)d_ws;
    float* syn_e = wsf + OFF_SYNE;
    float* syn_i = wsf + OFF_SYNI;
    u16*   spk1h = (u16*)(wsf + OFF_SPK1H);
    int*   cnt   = (int*)(wsf + OFF_CNT);
    float* syn2  = wsf + OFF_SYN2;
    u16*   spk2h = (u16*)(wsf + OFF_SPK2H);
    u16*   m2h   = (u16*)(wsf + OFF_M2H);
    u16*   m2l   = (u16*)(wsf + OFF_M2L);
    u16*   m2l2  = (u16*)(wsf + OFF_M2L2);
    u16*   wt    = (u16*)(wsf + OFF_WT);
    float* u     = wsf + OFF_U;
    float* cc    = wsf + OFF_CC;

    zero_ws_kernel<<<ZERO_W / 256, 256, 0, stream>>>(wsf, ZERO_W);
    wt_transform_kernel<<<432, 256, 0, stream>>>(w_conv, wt);

    // ---- t = 0 (algebraic) ----
    alpha_step_kernel<<<1152, 256, 0, stream>>>(
        (const float4*)x, p_alpha, p_beta, p_th1,
        (float4*)syn_e, (float4*)syn_i, spk1h);
    t0_u_kernel<<<1, COUT, 0, stream>>>(b_conv, u);
    t0_fillA_kernel<<<2304, 256, 0, stream>>>(u, bn_beta, (float4*)out);
    t0_fillB_kernel<<<2304, 256, 0, stream>>>(u, m2h, m2l, m2l2, (float4*)syn2);

    // ---- t = 1..3 ----
    for (int t = 1; t < T_; ++t) {
        alpha_step_kernel<<<1152, 256, 0, stream>>>(
            (const float4*)(x + (size_t)t * 1179648), p_alpha, p_beta, p_th1,
            (float4*)syn_e, (float4*)syn_i, spk1h);
        conv_mfma<<<2304, 256, 0, stream>>>(
            spk1h, m2h, m2l, m2l2, wt, cc);
        lstm_step_kernel<<<2304, 256, 0, stream>>>(
            cc, b_conv, p_th2, syn2, m2h, m2l, m2l2, spk2h, cnt + t * COUT);
        bn_step_kernel<<<2304, 256, 0, stream>>>(
            spk2h, cnt + t * COUT, gamma, bn_beta,
            (float4*)(out + (size_t)t * 2359296));
    }
}

// Round 10
// 753.765 us; speedup vs baseline: 3.4968x; 1.1133x over previous
//
#include <hip/hip_runtime.h>

// ---------------------------------------------------------------------------
// snnBlock, round 10: MFMA conv (r7-verified core) + in-block fused LSTM.
//  * nt = cg*4+gate => one block's 4 waves hold the 4 gates of the same 16
//    channels: 16KB LDS exchange (reusing alds) -> fused LSTM epilogue with
//    NO occupancy cost (still 1 nt per wave during MFMA).
//  * cc buffer eliminated (was 75 MB/step round-trip); lstm dispatch gone.
//  * m2 planes correctly sized (1179648 words each) + double-buffered —
//    fixes the r8/r9 overlap bug (planes were 589824 words apart, aliasing
//    each other and wt; masked only by the binary-spike output quantization).
// ---------------------------------------------------------------------------

typedef unsigned short u16;
typedef __attribute__((ext_vector_type(8))) __bf16 bf16x8;
typedef __attribute__((ext_vector_type(4))) float   f32x4;

#define T_ 4
#define B_ 8
#define CIN 64
#define COUT 128
#define H_ 48
#define W_ 48
#define HW 2304
#define NPIX 18432
#define KTOT 1728
#define WTPL 884736            // elements per weight plane

// ---- workspace layout (32-bit words); plane = 1179648 words ----
#define OFF_SYNE  0
#define OFF_SYNI  1179648
#define OFF_SPK1H 2359296      // bf16 [B][HW][64]  (589824 words)
#define OFF_CNT   2949120      // int [T][128]
#define ZERO_W    2949632
#define OFF_SYN2  2949632      // f32 fragment layout (2359296 words)
#define OFF_SPK2H 5308928      // bf16 [B][HW][128] (1179648 words)
#define OFF_M2H0  6488576      // bf16 [B][HW][128] planes, buffer 0
#define OFF_M2L0  7668224
#define OFF_M2L20 8847872
#define OFF_M2H1  10027520     // buffer 1
#define OFF_M2L1  11207168
#define OFF_M2L21 12386816
#define OFF_WT    13566464     // bf16 [3][884736] (1327104 words)
#define OFF_U     14893568     // 512 words
// end = 14894080 words = 59.6 MB (< 76.1 MB proven in r8)

static __device__ __forceinline__ u16 bfbits(float f) {
    __bf16 h = (__bf16)f; u16 u; __builtin_memcpy(&u, &h, 2); return u;
}
static __device__ __forceinline__ float bff(u16 u) {
    __bf16 h; __builtin_memcpy(&h, &u, 2); return (float)h;
}
static __device__ __forceinline__ f32x4 MFMA(bf16x8 a, bf16x8 b, f32x4 c) {
    return __builtin_amdgcn_mfma_f32_16x16x32_bf16(a, b, c, 0, 0, 0);
}

// ---------------------------------------------------------------------------
__global__ __launch_bounds__(256) void zero_ws_kernel(float* __restrict__ p, int n) {
    int i = blockIdx.x * 256 + threadIdx.x;
    if (i < n) p[i] = 0.0f;
}

// ---------------------------------------------------------------------------
// Weight transform (r7-verified): 3 bf16 planes in MFMA fragment order.
__global__ __launch_bounds__(256) void wt_transform_kernel(
        const float* __restrict__ w, u16* __restrict__ wt) {
    int id = blockIdx.x * 256 + threadIdx.x;      // 110592
    int lane = id & 63;
    int rest = id >> 6;                            // 1728
    int tap = rest % 9;
    int rest2 = rest / 9;                          // 192
    int ck = rest2 % 6, nt = rest2 / 6;            // nt 0..31
    int gate = nt & 3, cg = nt >> 2;
    int coutsub = lane & 15, kgl = lane >> 4;
    int oc = gate * COUT + cg * 16 + coutsub;
    int kh = tap / 3, kw = tap - kh * 3;
    size_t dst = ((size_t)(nt * 6 + ck) * 9 + tap) * 512 + lane * 8;
#pragma unroll
    for (int j = 0; j < 8; ++j) {
        int ch = ck * 32 + kgl * 8 + j;
        float wv = w[((oc * 192 + ch) * 3 + kh) * 3 + kw];
        float hh = (float)(__bf16)wv;
        float r1 = wv - hh;
        float ll = (float)(__bf16)r1;
        float r2 = r1 - ll;
        wt[dst + j]            = bfbits(hh);
        wt[WTPL + dst + j]     = bfbits(ll);
        wt[2 * WTPL + dst + j] = bfbits(r2);
    }
}

// ---------------------------------------------------------------------------
// Alpha neuron (unchanged).
__global__ __launch_bounds__(256) void alpha_step_kernel(
        const float4* __restrict__ x_t,
        const float* __restrict__ p_alpha, const float* __restrict__ p_beta,
        const float* __restrict__ p_th1,
        float4* __restrict__ syn_e, float4* __restrict__ syn_i,
        u16* __restrict__ spk1h) {
#pragma clang fp contract(off)
    int q = blockIdx.x * 256 + threadIdx.x;       // 294912 quads
    float a = fminf(fmaxf(p_alpha[0], 1e-6f), 1.0f - 1e-6f);
    float b = fminf(fmaxf(p_beta[0],  1e-6f), 1.0f - 1e-6f);
    float la = logf(a), lb = logf(b);
    float tau = la / (lb - la);
    float th1 = p_th1[0];

    int bc = q / 576;                              // b*64 + c
    int hw0 = (q - bc * 576) * 4;
    int bb = bc >> 6, c = bc & 63;
    u16* sp = spk1h + ((size_t)bb * HW + hw0) * 64 + c;

    float4 xv = x_t[q], e4 = syn_e[q], i4 = syn_i[q];
    float pr0 = bff(sp[0]), pr1 = bff(sp[64]), pr2 = bff(sp[128]), pr3 = bff(sp[192]);
    float e, ii, m1;
    u16 s0, s1, s2, s3;
    e = a * e4.x + xv.x; ii = b * i4.x - xv.x; m1 = tau * (e + ii) - pr0 * th1;
    e4.x = e; i4.x = ii; s0 = (m1 - th1) > 0.0f ? 0x3F80u : 0u;
    e = a * e4.y + xv.y; ii = b * i4.y - xv.y; m1 = tau * (e + ii) - pr1 * th1;
    e4.y = e; i4.y = ii; s1 = (m1 - th1) > 0.0f ? 0x3F80u : 0u;
    e = a * e4.z + xv.z; ii = b * i4.z - xv.z; m1 = tau * (e + ii) - pr2 * th1;
    e4.z = e; i4.z = ii; s2 = (m1 - th1) > 0.0f ? 0x3F80u : 0u;
    e = a * e4.w + xv.w; ii = b * i4.w - xv.w; m1 = tau * (e + ii) - pr3 * th1;
    e4.w = e; i4.w = ii; s3 = (m1 - th1) > 0.0f ? 0x3F80u : 0u;
    syn_e[q] = e4; syn_i[q] = i4;
    sp[0] = s0; sp[64] = s1; sp[128] = s2; sp[192] = s3;
}

// ---------------------------------------------------------------------------
// t=0: conv(all-zero input) = bias -> per-channel LSTM values.
__global__ void t0_u_kernel(const float* __restrict__ b_conv, float* __restrict__ u) {
#pragma clang fp contract(off)
    int c = threadIdx.x;                           // 128
    float gi = b_conv[c], gf = b_conv[COUT + c];
    float gg = b_conv[2 * COUT + c], go = b_conv[3 * COUT + c];
    float si = 1.0f / (1.0f + expf(-gi));
    float sf = 1.0f / (1.0f + expf(-gf));
    float so = 1.0f / (1.0f + expf(-go));
    float tg = tanhf(gg);
    float s2 = sf * 0.0f + si * tg;
    float m2 = so * tanhf(s2);
    u[c] = s2;
    u16* uh = (u16*)(u + 128);
    float hh = (float)(__bf16)m2;
    float r1 = m2 - hh;
    float ll = (float)(__bf16)r1;
    float r2 = r1 - ll;
    uh[c] = bfbits(hh); uh[128 + c] = bfbits(ll); uh[256 + c] = bfbits(r2);
}

// t=0 fill A: out(t0) = bn_beta[c] (ch-major, matches output layout).
__global__ __launch_bounds__(256) void t0_fillA_kernel(
        const float* __restrict__ u, const float* __restrict__ bnb,
        float4* __restrict__ out0) {
    int i = blockIdx.x * 256 + threadIdx.x;        // 589824 quads
    int c = ((i * 4) / HW) % COUT;
    float bb = bnb[c];
    out0[i] = make_float4(bb, bb, bb, bb);
}

// t=0 fill B: m2 planes buffer 0 (pixel-major) + syn2 (fragment layout).
__global__ __launch_bounds__(256) void t0_fillB_kernel(
        const float* __restrict__ u,
        u16* __restrict__ mh, u16* __restrict__ ml, u16* __restrict__ ml2,
        float4* __restrict__ syn2) {
    int i = blockIdx.x * 256 + threadIdx.x;        // 589824
    {   // m2 planes: 4 channels of one pixel
        int pg = i >> 5, c0 = (i & 31) * 4;
        const u16* uh = (const u16*)(u + 128);
        uint2 vh  = *(const uint2*)(uh + c0);
        uint2 vl  = *(const uint2*)(uh + 128 + c0);
        uint2 vl2 = *(const uint2*)(uh + 256 + c0);
        *(uint2*)(mh  + (size_t)pg * 128 + c0) = vh;
        *(uint2*)(ml  + (size_t)pg * 128 + c0) = vl;
        *(uint2*)(ml2 + (size_t)pg * 128 + c0) = vl2;
    }
    {   // syn2 fragment layout: c = ((i>>8)&7)*16 + (i&15)
        int c = ((i >> 8) & 7) * 16 + (i & 15);
        float s2 = u[c];
        syn2[i] = make_float4(s2, s2, s2, s2);
    }
}

// ---------------------------------------------------------------------------
// MFMA conv + in-block fused LSTM. Block: 4 waves, wave = 1 nt (N=16), M=64.
// Grid 2304: bx = ntq*288 + mt*8 + b  ->  XCD = bx%8 = b.
// Waves of one block hold nt = ntq*4+{0..3} = the 4 gates of cg = ntq:
// gate exchange via 16KB LDS (alds reuse) -> fused LSTM, no cc buffer.
__global__ __launch_bounds__(256, 4) void conv_lstm_fused(
        const u16* __restrict__ spk1h,
        const u16* __restrict__ m2h, const u16* __restrict__ m2l,
        const u16* __restrict__ m2l2,
        const u16* __restrict__ wt,
        const float* __restrict__ bias, const float* __restrict__ p_th2,
        float* __restrict__ syn2,
        u16* __restrict__ o_m2h, u16* __restrict__ o_m2l, u16* __restrict__ o_m2l2,
        u16* __restrict__ spk2h, int* __restrict__ cnt) {
    __shared__ __align__(16) u16 alds[3][4320];    // staging; reused as f32[4096]

    const int bx  = blockIdx.x;
    const int ntq = bx / 288;
    const int rm  = bx - ntq * 288;                // mt*8 + b
    const int mt  = rm >> 3;
    const int b   = rm & 7;
    const int mt3 = mt / 3;
    const int h0 = mt3 * 4, w0 = (mt - mt3 * 3) * 16;

    const int tid = threadIdx.x;
    const int wn  = tid >> 6;
    const int lane = tid & 63;
    const int m16 = lane & 15;
    const int kg  = lane >> 4;
    const size_t pxbase = (size_t)b * HW;
    const int nt = ntq * 4 + wn;                   // cg = ntq, gate = wn

    f32x4 acc[4];
#pragma unroll
    for (int mf = 0; mf < 4; ++mf) acc[mf] = (f32x4){0.f, 0.f, 0.f, 0.f};

    // ---------------- binary chunks (spk1, ck 0..1): 3-term ----------------
    for (int ck = 0; ck < 2; ++ck) {
        __syncthreads();
        {
            const u16* s0 = spk1h + pxbase * 64 + ck * 32;
            for (int i = tid; i < 432; i += 256) {
                int px = i >> 2, qt = i & 3;
                int rr = px / 18, ccx = px - rr * 18;
                int gh = h0 - 1 + rr, gw = w0 - 1 + ccx;
                uint4 v = make_uint4(0u, 0u, 0u, 0u);
                if ((unsigned)gh < 48u && (unsigned)gw < 48u)
                    v = *(const uint4*)(s0 + (size_t)(gh * 48 + gw) * 64 + qt * 8);
                *(uint4*)&alds[0][px * 40 + qt * 8] = v;
            }
        }
        __syncthreads();
#pragma unroll
        for (int kh = 0; kh < 3; ++kh)
#pragma unroll
        for (int kw = 0; kw < 3; ++kw) {
            bf16x8 Ah[4];
#pragma unroll
            for (int mf = 0; mf < 4; ++mf)
                Ah[mf] = *(const bf16x8*)&alds[0][((mf + kh) * 18 + m16 + kw) * 40 + kg * 8];
            const size_t bo = ((size_t)(nt * 6 + ck) * 9 + (kh * 3 + kw)) * 512 + lane * 8;
            bf16x8 Bh  = *(const bf16x8*)(wt + bo);
            bf16x8 Bl  = *(const bf16x8*)(wt + WTPL + bo);
            bf16x8 Bl2 = *(const bf16x8*)(wt + 2 * WTPL + bo);
#pragma unroll
            for (int mf = 0; mf < 4; ++mf) acc[mf] = MFMA(Ah[mf], Bh,  acc[mf]);
#pragma unroll
            for (int mf = 0; mf < 4; ++mf) acc[mf] = MFMA(Ah[mf], Bl,  acc[mf]);
#pragma unroll
            for (int mf = 0; mf < 4; ++mf) acc[mf] = MFMA(Ah[mf], Bl2, acc[mf]);
        }
    }

    // ---------------- mem2 chunks (ck 2..5): 7-term ----------------
    for (int ck = 2; ck < 6; ++ck) {
        __syncthreads();
        {
            const int ch0 = (ck - 2) * 32;
            const u16* s0 = m2h  + pxbase * 128 + ch0;
            const u16* s1 = m2l  + pxbase * 128 + ch0;
            const u16* s2 = m2l2 + pxbase * 128 + ch0;
            for (int i = tid; i < 1296; i += 256) {
                int pl = i / 432;
                int r = i - pl * 432;
                int px = r >> 2, qt = r & 3;
                int rr = px / 18, ccx = px - rr * 18;
                int gh = h0 - 1 + rr, gw = w0 - 1 + ccx;
                uint4 v = make_uint4(0u, 0u, 0u, 0u);
                if ((unsigned)gh < 48u && (unsigned)gw < 48u) {
                    const u16* sp = (pl == 0 ? s0 : (pl == 1 ? s1 : s2));
                    v = *(const uint4*)(sp + (size_t)(gh * 48 + gw) * 128 + qt * 8);
                }
                *(uint4*)&alds[pl][px * 40 + qt * 8] = v;
            }
        }
        __syncthreads();
#pragma unroll
        for (int kh = 0; kh < 3; ++kh)
#pragma unroll
        for (int kw = 0; kw < 3; ++kw) {
            bf16x8 Ah[4], Al[4], Al2[4];
#pragma unroll
            for (int mf = 0; mf < 4; ++mf) {
                const int ai = ((mf + kh) * 18 + m16 + kw) * 40 + kg * 8;
                Ah[mf]  = *(const bf16x8*)&alds[0][ai];
                Al[mf]  = *(const bf16x8*)&alds[1][ai];
                Al2[mf] = *(const bf16x8*)&alds[2][ai];
            }
            const size_t bo = ((size_t)(nt * 6 + ck) * 9 + (kh * 3 + kw)) * 512 + lane * 8;
            bf16x8 Bh  = *(const bf16x8*)(wt + bo);
            bf16x8 Bl  = *(const bf16x8*)(wt + WTPL + bo);
            bf16x8 Bl2 = *(const bf16x8*)(wt + 2 * WTPL + bo);
#pragma unroll
            for (int mf = 0; mf < 4; ++mf) acc[mf] = MFMA(Ah[mf],  Bh,  acc[mf]);
#pragma unroll
            for (int mf = 0; mf < 4; ++mf) acc[mf] = MFMA(Ah[mf],  Bl,  acc[mf]);
#pragma unroll
            for (int mf = 0; mf < 4; ++mf) acc[mf] = MFMA(Ah[mf],  Bl2, acc[mf]);
#pragma unroll
            for (int mf = 0; mf < 4; ++mf) acc[mf] = MFMA(Al[mf],  Bh,  acc[mf]);
#pragma unroll
            for (int mf = 0; mf < 4; ++mf) acc[mf] = MFMA(Al[mf],  Bl,  acc[mf]);
#pragma unroll
            for (int mf = 0; mf < 4; ++mf) acc[mf] = MFMA(Al2[mf], Bh,  acc[mf]);
#pragma unroll
            for (int mf = 0; mf < 4; ++mf) acc[mf] = MFMA(Al2[mf], Bl,  acc[mf]);
        }
    }

    // ---- exchange gate fragments through LDS (wave wn holds gate wn) ----
    __syncthreads();
    {
        float* glds = (float*)alds;                // 16 KB of the 25.9 KB
#pragma unroll
        for (int mf = 0; mf < 4; ++mf)
            *(f32x4*)(glds + (wn * 4 + mf) * 256 + lane * 4) = acc[mf];
    }
    __syncthreads();

    // ---- fused LSTM epilogue: wave wn processes row mf = wn ----
    {
#pragma clang fp contract(off)
        const float* glds = (const float*)alds;
        const int mf = wn;
        const f32x4 vI = *(const f32x4*)(glds + (0 * 4 + mf) * 256 + lane * 4);
        const f32x4 vF = *(const f32x4*)(glds + (1 * 4 + mf) * 256 + lane * 4);
        const f32x4 vG = *(const f32x4*)(glds + (2 * 4 + mf) * 256 + lane * 4);
        const f32x4 vO = *(const f32x4*)(glds + (3 * 4 + mf) * 256 + lane * 4);
        const int c = ntq * 16 + m16;
        const float th2 = p_th2[0];
        const float b0 = bias[c],       b1 = bias[128 + c];
        const float b2 = bias[256 + c], b3 = bias[384 + c];
        // syn2 fragment layout (matches t0_fillB / r9-verified mapping)
        const size_t sidx = ((size_t)((b * 36 + mt) * 32 + ntq * 4 + mf) * 64 + lane) * 4;
        const f32x4 s2v = *(const f32x4*)(syn2 + sidx);
        const int h = h0 + mf;
        const size_t pixbase = ((size_t)b * HW + h * 48 + w0 + kg * 4) * 128 + c;

        f32x4 s2o;
        int sc = 0;
#pragma unroll
        for (int j = 0; j < 4; ++j) {
            float gi = vI[j] + b0, gf = vF[j] + b1;
            float gg = vG[j] + b2, go = vO[j] + b3;
            float si = 1.0f / (1.0f + expf(-gi));
            float sf = 1.0f / (1.0f + expf(-gf));
            float so = 1.0f / (1.0f + expf(-go));
            float tg = tanhf(gg);
            float s2 = sf * s2v[j] + si * tg;
            float m2 = so * tanhf(s2);
            s2o[j] = s2;
            float hh = (float)(__bf16)m2;
            float r1 = m2 - hh;
            float ll = (float)(__bf16)r1;
            float r2 = r1 - ll;
            const size_t pix = pixbase + (size_t)j * 128;
            o_m2h[pix]  = bfbits(hh);
            o_m2l[pix]  = bfbits(ll);
            o_m2l2[pix] = bfbits(r2);
            bool sp = (m2 - th2) > 0.0f;
            spk2h[pix] = sp ? 0x3F80u : 0u;
            sc += sp ? 1 : 0;
        }
        *(f32x4*)(syn2 + sidx) = s2o;
        // reduce over kg (lane bits 4,5): lanes<16 hold this wave's channel sum
        sc += __shfl_xor(sc, 16);
        sc += __shfl_xor(sc, 32);
        if (lane < 16) atomicAdd(&cnt[c], sc);
    }
}

// ---------------------------------------------------------------------------
// BN of binary spikes: mu = cnt/NPIX exact, var = mu - mu^2; reads pm bf16.
__global__ __launch_bounds__(256) void bn_step_kernel(
        const u16* __restrict__ spk2h, const int* __restrict__ cnt,
        const float* __restrict__ gamma, const float* __restrict__ bnb,
        float4* __restrict__ out) {
#pragma clang fp contract(off)
    int i = blockIdx.x * 256 + threadIdx.x;        // 589824 quads (ch-major out)
    int e = i * 4;
    int tmp = e / HW;                               // b*128 + c
    int bb = tmp >> 7, c = tmp & 127;
    int hw0 = e - tmp * HW;
    const u16* sp = spk2h + ((size_t)bb * HW + hw0) * 128 + c;
    float mu  = (float)cnt[c] / (float)NPIX;
    float var = mu - mu * mu;
    float rs  = rsqrtf(var + 1e-5f);
    float g = gamma[c], bv = bnb[c];
    float s0 = bff(sp[0]), s1 = bff(sp[128]), s2 = bff(sp[256]), s3 = bff(sp[384]);
    out[i] = make_float4(g * (s0 - mu) * rs + bv, g * (s1 - mu) * rs + bv,
                         g * (s2 - mu) * rs + bv, g * (s3 - mu) * rs + bv);
}

// ---------------------------------------------------------------------------
extern "C" void kernel_launch(void* const* d_in, const int* in_sizes, int n_in,
                              void* d_out, int out_size, void* d_ws, size_t ws_size,
                              hipStream_t stream) {
    const float* x       = (const float*)d_in[0];
    const float* p_alpha = (const float*)d_in[1];
    const float* p_beta  = (const float*)d_in[2];
    const float* p_th1   = (const float*)d_in[3];
    const float* p_th2   = (const float*)d_in[4];
    const float* w_conv  = (const float*)d_in[5];
    const float* b_conv  = (const float*)d_in[6];
    const float* gamma   = (const float*)d_in[7];
    const float* bn_beta = (const float*)d_in[8];
    float* out = (float*)d_out;

    float* wsf   = (float*)d_ws;
    float* syn_e = wsf + OFF_SYNE;
    float* syn_i = wsf + OFF_SYNI;
    u16*   spk1h = (u16*)(wsf + OFF_SPK1H);
    int*   cnt   = (int*)(wsf + OFF_CNT);
    float* syn2  = wsf + OFF_SYN2;
    u16*   spk2h = (u16*)(wsf + OFF_SPK2H);
    u16*   mh[2]  = {(u16*)(wsf + OFF_M2H0),  (u16*)(wsf + OFF_M2H1)};
    u16*   ml[2]  = {(u16*)(wsf + OFF_M2L0),  (u16*)(wsf + OFF_M2L1)};
    u16*   ml2[2] = {(u16*)(wsf + OFF_M2L20), (u16*)(wsf + OFF_M2L21)};
    u16*   wt    = (u16*)(wsf + OFF_WT);
    float* u     = wsf + OFF_U;

    zero_ws_kernel<<<ZERO_W / 256, 256, 0, stream>>>(wsf, ZERO_W);
    wt_transform_kernel<<<432, 256, 0, stream>>>(w_conv, wt);

    // ---- t = 0 (algebraic) ----
    alpha_step_kernel<<<1152, 256, 0, stream>>>(
        (const float4*)x, p_alpha, p_beta, p_th1,
        (float4*)syn_e, (float4*)syn_i, spk1h);
    t0_u_kernel<<<1, COUT, 0, stream>>>(b_conv, u);
    t0_fillA_kernel<<<2304, 256, 0, stream>>>(u, bn_beta, (float4*)out);
    t0_fillB_kernel<<<2304, 256, 0, stream>>>(u, mh[0], ml[0], ml2[0], (float4*)syn2);

    // ---- t = 1..3 ----
    for (int t = 1; t < T_; ++t) {
        const int rd = (t - 1) & 1, wr = t & 1;
        alpha_step_kernel<<<1152, 256, 0, stream>>>(
            (const float4*)(x + (size_t)t * 1179648), p_alpha, p_beta, p_th1,
            (float4*)syn_e, (float4*)syn_i, spk1h);
        conv_lstm_fused<<<2304, 256, 0, stream>>>(
            spk1h, mh[rd], ml[rd], ml2[rd], wt, b_conv, p_th2,
            syn2, mh[wr], ml[wr], ml2[wr], spk2h, cnt + t * COUT);
        bn_step_kernel<<<2304, 256, 0, stream>>>(
            spk2h, cnt + t * COUT, gamma, bn_beta,
            (float4*)(out + (size_t)t * 2359296));
    }
}

// Round 11
// 482.213 us; speedup vs baseline: 5.4660x; 1.5631x over previous
//
#include <hip/hip_runtime.h>

// ---------------------------------------------------------------------------
// snnBlock, round 11: M=128 MFMA conv + fused LSTM, pipelined staging.
//  * 8x16 px tile per block (2448 MFMA/wave), rolling A-window (LDS reads
//    minimized), B-frags hoisted per (kw,kh), reg-prefetch of next chunk's
//    staging under current chunk's MFMAs (r4-proven single-owner pipeline).
//  * activations in 16-channel-blocked layouts [B][cg][HW][16] -> every
//    64B line written by exactly one wave (kills multi-phase line RMW).
//  * LDS *content* identical to r7-verified layout -> identical fragments.
// ---------------------------------------------------------------------------

typedef unsigned short u16;
typedef __attribute__((ext_vector_type(8))) __bf16 bf16x8;
typedef __attribute__((ext_vector_type(4))) float   f32x4;

#define T_ 4
#define B_ 8
#define CIN 64
#define COUT 128
#define H_ 48
#define W_ 48
#define HW 2304
#define NPIX 18432
#define KTOT 1728
#define WTPL 884736            // elements per weight plane
#define M2PL 2359296           // u16 per m2 plane [B][8][HW][16]

// ---- workspace layout (32-bit words) ----
#define OFF_SYNE  0
#define OFF_SYNI  1179648
#define OFF_SPK1H 2359296      // bf16 [B][4][HW][16]
#define OFF_CNT   2949120      // int [T][128]
#define ZERO_W    2949632
#define OFF_SYN2  2949632      // f32 fragment layout (2359296 words)
#define OFF_SPK2H 5308928      // bf16 [B][8][HW][16]
#define OFF_M2H0  6488576      // 3 contiguous planes, buffer 0
#define OFF_M2L0  7668224
#define OFF_M2L20 8847872
#define OFF_M2H1  10027520     // 3 contiguous planes, buffer 1
#define OFF_M2L1  11207168
#define OFF_M2L21 12386816
#define OFF_WT    13566464     // bf16 [3][884736]
#define OFF_U     14893568

static __device__ __forceinline__ u16 bfbits(float f) {
    __bf16 h = (__bf16)f; u16 u; __builtin_memcpy(&u, &h, 2); return u;
}
static __device__ __forceinline__ float bff(u16 u) {
    __bf16 h; __builtin_memcpy(&h, &u, 2); return (float)h;
}
static __device__ __forceinline__ f32x4 MFMA(bf16x8 a, bf16x8 b, f32x4 c) {
    return __builtin_amdgcn_mfma_f32_16x16x32_bf16(a, b, c, 0, 0, 0);
}

// ---------------------------------------------------------------------------
__global__ __launch_bounds__(256) void zero_ws_kernel(float* __restrict__ p, int n) {
    int i = blockIdx.x * 256 + threadIdx.x;
    if (i < n) p[i] = 0.0f;
}

// ---------------------------------------------------------------------------
// Weight transform (r7-verified, unchanged).
__global__ __launch_bounds__(256) void wt_transform_kernel(
        const float* __restrict__ w, u16* __restrict__ wt) {
    int id = blockIdx.x * 256 + threadIdx.x;      // 110592
    int lane = id & 63;
    int rest = id >> 6;
    int tap = rest % 9;
    int rest2 = rest / 9;
    int ck = rest2 % 6, nt = rest2 / 6;
    int gate = nt & 3, cg = nt >> 2;
    int coutsub = lane & 15, kgl = lane >> 4;
    int oc = gate * COUT + cg * 16 + coutsub;
    int kh = tap / 3, kw = tap - kh * 3;
    size_t dst = ((size_t)(nt * 6 + ck) * 9 + tap) * 512 + lane * 8;
#pragma unroll
    for (int j = 0; j < 8; ++j) {
        int ch = ck * 32 + kgl * 8 + j;
        float wv = w[((oc * 192 + ch) * 3 + kh) * 3 + kw];
        float hh = (float)(__bf16)wv;
        float r1 = wv - hh;
        float ll = (float)(__bf16)r1;
        float r2 = r1 - ll;
        wt[dst + j]            = bfbits(hh);
        wt[WTPL + dst + j]     = bfbits(ll);
        wt[2 * WTPL + dst + j] = bfbits(r2);
    }
}

// ---------------------------------------------------------------------------
// Alpha neuron; spk1 now [B][4][HW][16] (16-channel-blocked).
__global__ __launch_bounds__(256) void alpha_step_kernel(
        const float4* __restrict__ x_t,
        const float* __restrict__ p_alpha, const float* __restrict__ p_beta,
        const float* __restrict__ p_th1,
        float4* __restrict__ syn_e, float4* __restrict__ syn_i,
        u16* __restrict__ spk1h) {
#pragma clang fp contract(off)
    int q = blockIdx.x * 256 + threadIdx.x;       // 294912 quads
    float a = fminf(fmaxf(p_alpha[0], 1e-6f), 1.0f - 1e-6f);
    float b = fminf(fmaxf(p_beta[0],  1e-6f), 1.0f - 1e-6f);
    float la = logf(a), lb = logf(b);
    float tau = la / (lb - la);
    float th1 = p_th1[0];

    int bc = q / 576;                              // b*64 + c
    int hw0 = (q - bc * 576) * 4;
    int bb = bc >> 6, c = bc & 63;
    u16* sp = spk1h + ((size_t)(bb * 4 + (c >> 4)) * HW + hw0) * 16 + (c & 15);

    float4 xv = x_t[q], e4 = syn_e[q], i4 = syn_i[q];
    float pr0 = bff(sp[0]), pr1 = bff(sp[16]), pr2 = bff(sp[32]), pr3 = bff(sp[48]);
    float e, ii, m1;
    u16 s0, s1, s2, s3;
    e = a * e4.x + xv.x; ii = b * i4.x - xv.x; m1 = tau * (e + ii) - pr0 * th1;
    e4.x = e; i4.x = ii; s0 = (m1 - th1) > 0.0f ? 0x3F80u : 0u;
    e = a * e4.y + xv.y; ii = b * i4.y - xv.y; m1 = tau * (e + ii) - pr1 * th1;
    e4.y = e; i4.y = ii; s1 = (m1 - th1) > 0.0f ? 0x3F80u : 0u;
    e = a * e4.z + xv.z; ii = b * i4.z - xv.z; m1 = tau * (e + ii) - pr2 * th1;
    e4.z = e; i4.z = ii; s2 = (m1 - th1) > 0.0f ? 0x3F80u : 0u;
    e = a * e4.w + xv.w; ii = b * i4.w - xv.w; m1 = tau * (e + ii) - pr3 * th1;
    e4.w = e; i4.w = ii; s3 = (m1 - th1) > 0.0f ? 0x3F80u : 0u;
    syn_e[q] = e4; syn_i[q] = i4;
    sp[0] = s0; sp[16] = s1; sp[32] = s2; sp[48] = s3;
}

// ---------------------------------------------------------------------------
__global__ void t0_u_kernel(const float* __restrict__ b_conv, float* __restrict__ u) {
#pragma clang fp contract(off)
    int c = threadIdx.x;                           // 128
    float gi = b_conv[c], gf = b_conv[COUT + c];
    float gg = b_conv[2 * COUT + c], go = b_conv[3 * COUT + c];
    float si = 1.0f / (1.0f + expf(-gi));
    float sf = 1.0f / (1.0f + expf(-gf));
    float so = 1.0f / (1.0f + expf(-go));
    float tg = tanhf(gg);
    float s2 = sf * 0.0f + si * tg;
    float m2 = so * tanhf(s2);
    u[c] = s2;
    u16* uh = (u16*)(u + 128);
    float hh = (float)(__bf16)m2;
    float r1 = m2 - hh;
    float ll = (float)(__bf16)r1;
    float r2 = r1 - ll;
    uh[c] = bfbits(hh); uh[128 + c] = bfbits(ll); uh[256 + c] = bfbits(r2);
}

__global__ __launch_bounds__(256) void t0_fillA_kernel(
        const float* __restrict__ u, const float* __restrict__ bnb,
        float4* __restrict__ out0) {
    int i = blockIdx.x * 256 + threadIdx.x;        // 589824 quads
    int c = ((i * 4) / HW) % COUT;
    float bb = bnb[c];
    out0[i] = make_float4(bb, bb, bb, bb);
}

// t=0 fill B: m2 planes buffer 0 (16-ch-blocked) + syn2 (fragment layout).
__global__ __launch_bounds__(256) void t0_fillB_kernel(
        const float* __restrict__ u,
        u16* __restrict__ m2, float4* __restrict__ syn2) {
    int i = blockIdx.x * 256 + threadIdx.x;        // 589824
    const u16* uh = (const u16*)(u + 128);
    int pxg = i >> 2;
    int cg = (pxg / HW) & 7;
    int c0 = cg * 16 + (i & 3) * 4;
    *(uint2*)(m2 + (size_t)i * 4)             = *(const uint2*)(uh + c0);
    *(uint2*)(m2 + M2PL + (size_t)i * 4)      = *(const uint2*)(uh + 128 + c0);
    *(uint2*)(m2 + 2 * M2PL + (size_t)i * 4)  = *(const uint2*)(uh + 256 + c0);
    int csy = ((i >> 9) & 7) * 16 + (i & 15);
    float s2 = u[csy];
    syn2[i] = make_float4(s2, s2, s2, s2);
}

// ---------------------------------------------------------------------------
// MFMA conv + fused LSTM. Block: 4 waves, wave = 1 nt, M=128 px (8x16 tile).
// Grid 1152: bx = ntq*144 + mt*8 + b -> XCD = b.
#define LDSROW(P, r, kw) (*(const bf16x8*)&alds[P][(((r) * 18) + m16 + (kw)) * 40 + kg * 8])
__global__ __launch_bounds__(256, 3) void conv_lstm_fused(
        const u16* __restrict__ spk1h,
        const u16* __restrict__ m2rd,      // base of 3 contiguous planes
        const u16* __restrict__ wt,
        const float* __restrict__ bias, const float* __restrict__ p_th2,
        float* __restrict__ syn2,
        u16* __restrict__ m2wr,            // base of 3 contiguous planes
        u16* __restrict__ spk2h, int* __restrict__ cnt) {
    __shared__ __align__(16) u16 alds[3][7200];    // 43.2 KB; reused as f32 glds

    const int bx  = blockIdx.x;
    const int ntq = bx / 144;
    const int rm  = bx - ntq * 144;
    const int mt  = rm >> 3;
    const int b   = rm & 7;
    const int mt3 = mt / 3;
    const int h0 = mt3 * 8, w0 = (mt - mt3 * 3) * 16;

    const int tid = threadIdx.x;
    const int wn  = tid >> 6;
    const int lane = tid & 63;
    const int m16 = lane & 15;
    const int kg  = lane >> 4;
    const int nt = ntq * 4 + wn;

    f32x4 acc[8];
#pragma unroll
    for (int mf = 0; mf < 8; ++mf) acc[mf] = (f32x4){0.f, 0.f, 0.f, 0.f};

    // ---- hoisted mem2 staging indices (chunk-invariant except cg shift) ----
    int ldsM[9], srcM[9];
#pragma unroll
    for (int j = 0; j < 9; ++j) {
        int i = tid + j * 256;
        int pl = i / 720;
        int r = i - pl * 720;
        int px = r >> 2, qt = r & 3;
        int rr = px / 18, cc2 = px - rr * 18;
        int gh = h0 - 1 + rr, gw = w0 - 1 + cc2;
        ldsM[j] = (i < 2160) ? (pl * 7200 + px * 40 + qt * 8) : -1;
        bool ok = (i < 2160) && ((unsigned)gh < 48u) && ((unsigned)gw < 48u);
        srcM[j] = ok ? (pl * M2PL + ((b * 8 + (qt >> 1)) * HW + gh * 48 + gw) * 16
                        + (qt & 1) * 8) : -1;
    }

    // ---- binary staging: ck 0,1 -> planes 0,1 (one shot) ----
    {
        uint4 stB[6]; int ldsB[6];
#pragma unroll
        for (int j = 0; j < 6; ++j) {
            int i = tid + j * 256;
            int ckb = i / 720;
            int r = i - ckb * 720;
            int px = r >> 2, qt = r & 3;
            int rr = px / 18, cc2 = px - rr * 18;
            int gh = h0 - 1 + rr, gw = w0 - 1 + cc2;
            ldsB[j] = (i < 1440) ? (ckb * 7200 + px * 40 + qt * 8) : -1;
            uint4 v = make_uint4(0u, 0u, 0u, 0u);
            if (i < 1440 && (unsigned)gh < 48u && (unsigned)gw < 48u)
                v = *(const uint4*)(spk1h
                    + ((size_t)(b * 4 + ckb * 2 + (qt >> 1)) * HW + gh * 48 + gw) * 16
                    + (qt & 1) * 8);
            stB[j] = v;
        }
#pragma unroll
        for (int j = 0; j < 6; ++j)
            if (ldsB[j] >= 0) *(uint4*)&alds[0][ldsB[j]] = stB[j];
    }
    __syncthreads();

    uint4 stM[9];
#define LOADM(ck_)                                                           \
    {                                                                        \
        const int add = ((ck_) - 2) * (2 * HW * 16);                         \
        _Pragma("unroll")                                                    \
        for (int j = 0; j < 9; ++j) {                                        \
            uint4 v = make_uint4(0u, 0u, 0u, 0u);                            \
            if (srcM[j] >= 0) v = *(const uint4*)(m2rd + srcM[j] + add);     \
            stM[j] = v;                                                      \
        }                                                                    \
    }
#define WRITEM                                                               \
    {                                                                        \
        _Pragma("unroll")                                                    \
        for (int j = 0; j < 9; ++j)                                          \
            if (ldsM[j] >= 0) *(uint4*)&alds[0][ldsM[j]] = stM[j];           \
    }

    LOADM(2);                                      // in flight under binary compute

    // ---- binary compute (3-term), planes 0,1 ----
    for (int ckb = 0; ckb < 2; ++ckb) {
#pragma unroll
        for (int kw = 0; kw < 3; ++kw) {
            bf16x8 B0[3], B1[3], B2[3];
#pragma unroll
            for (int kh = 0; kh < 3; ++kh) {
                const size_t bo = ((size_t)(nt * 6 + ckb) * 9 + kh * 3 + kw) * 512 + lane * 8;
                B0[kh] = *(const bf16x8*)(wt + bo);
                B1[kh] = *(const bf16x8*)(wt + WTPL + bo);
                B2[kh] = *(const bf16x8*)(wt + 2 * WTPL + bo);
            }
            bf16x8 aw[3];
            aw[0] = LDSROW(ckb, 0, kw);
            aw[1] = LDSROW(ckb, 1, kw);
#pragma unroll
            for (int mf = 0; mf < 8; ++mf) {
                aw[(mf + 2) % 3] = LDSROW(ckb, mf + 2, kw);
#pragma unroll
                for (int kh = 0; kh < 3; ++kh) {
                    const bf16x8 A = aw[(mf + kh) % 3];
                    acc[mf] = MFMA(A, B0[kh], acc[mf]);
                    acc[mf] = MFMA(A, B1[kh], acc[mf]);
                    acc[mf] = MFMA(A, B2[kh], acc[mf]);
                }
            }
        }
    }

    // ---- mem2 chunks (7-term), pipelined staging ----
    for (int ck = 2; ck < 6; ++ck) {
        __syncthreads();
        WRITEM;
        __syncthreads();
        if (ck < 5) LOADM(ck + 1);
#pragma unroll
        for (int kw = 0; kw < 3; ++kw) {
            bf16x8 B0[3], B1[3], B2[3];
#pragma unroll
            for (int kh = 0; kh < 3; ++kh) {
                const size_t bo = ((size_t)(nt * 6 + ck) * 9 + kh * 3 + kw) * 512 + lane * 8;
                B0[kh] = *(const bf16x8*)(wt + bo);
                B1[kh] = *(const bf16x8*)(wt + WTPL + bo);
                B2[kh] = *(const bf16x8*)(wt + 2 * WTPL + bo);
            }
            bf16x8 a0[3], a1[3], a2[3];
            a0[0] = LDSROW(0, 0, kw); a0[1] = LDSROW(0, 1, kw);
            a1[0] = LDSROW(1, 0, kw); a1[1] = LDSROW(1, 1, kw);
            a2[0] = LDSROW(2, 0, kw); a2[1] = LDSROW(2, 1, kw);
#pragma unroll
            for (int mf = 0; mf < 8; ++mf) {
                const int sn = (mf + 2) % 3;
                a0[sn] = LDSROW(0, mf + 2, kw);
                a1[sn] = LDSROW(1, mf + 2, kw);
                a2[sn] = LDSROW(2, mf + 2, kw);
#pragma unroll
                for (int kh = 0; kh < 3; ++kh) {
                    const int s = (mf + kh) % 3;
                    acc[mf] = MFMA(a0[s], B0[kh], acc[mf]);
                    acc[mf] = MFMA(a0[s], B1[kh], acc[mf]);
                    acc[mf] = MFMA(a0[s], B2[kh], acc[mf]);
                    acc[mf] = MFMA(a1[s], B0[kh], acc[mf]);
                    acc[mf] = MFMA(a1[s], B1[kh], acc[mf]);
                    acc[mf] = MFMA(a2[s], B0[kh], acc[mf]);
                    acc[mf] = MFMA(a2[s], B1[kh], acc[mf]);
                }
            }
        }
    }

    // ---- gate exchange through LDS, then fused LSTM ----
    __syncthreads();
    {
        float* glds = (float*)alds;
#pragma unroll
        for (int mf = 0; mf < 8; ++mf)
            *(f32x4*)(glds + (wn * 8 + mf) * 256 + lane * 4) = acc[mf];
    }
    __syncthreads();
    {
#pragma clang fp contract(off)
        const float* glds = (const float*)alds;
        const int c = ntq * 16 + m16;
        const float th2 = p_th2[0];
        const float b0 = bias[c],       b1 = bias[128 + c];
        const float b2 = bias[256 + c], b3 = bias[384 + c];
        int sc = 0;
#pragma unroll
        for (int q = 0; q < 2; ++q) {
            const int mfq = wn * 2 + q;
            const f32x4 vI = *(const f32x4*)(glds + (0 * 8 + mfq) * 256 + lane * 4);
            const f32x4 vF = *(const f32x4*)(glds + (1 * 8 + mfq) * 256 + lane * 4);
            const f32x4 vG = *(const f32x4*)(glds + (2 * 8 + mfq) * 256 + lane * 4);
            const f32x4 vO = *(const f32x4*)(glds + (3 * 8 + mfq) * 256 + lane * 4);
            const size_t sidx = ((size_t)(((b * 18 + mt) * 8 + ntq) * 8 + mfq) * 64 + lane) * 4;
            const f32x4 s2v = *(const f32x4*)(syn2 + sidx);
            const int h = h0 + mfq;
            const size_t pixb = ((size_t)(b * 8 + ntq) * HW + h * 48 + w0 + kg * 4) * 16 + m16;
            f32x4 s2o;
#pragma unroll
            for (int j = 0; j < 4; ++j) {
                float gi = vI[j] + b0, gf = vF[j] + b1;
                float gg = vG[j] + b2, go = vO[j] + b3;
                float si = 1.0f / (1.0f + expf(-gi));
                float sf = 1.0f / (1.0f + expf(-gf));
                float so = 1.0f / (1.0f + expf(-go));
                float tg = tanhf(gg);
                float s2 = sf * s2v[j] + si * tg;
                float m2 = so * tanhf(s2);
                s2o[j] = s2;
                float hh = (float)(__bf16)m2;
                float r1 = m2 - hh;
                float ll = (float)(__bf16)r1;
                float r2 = r1 - ll;
                const size_t pix = pixb + (size_t)j * 16;
                m2wr[pix]             = bfbits(hh);
                m2wr[M2PL + pix]      = bfbits(ll);
                m2wr[2 * M2PL + pix]  = bfbits(r2);
                bool sp = (m2 - th2) > 0.0f;
                spk2h[pix] = sp ? 0x3F80u : 0u;
                sc += sp ? 1 : 0;
            }
            *(f32x4*)(syn2 + sidx) = s2o;
        }
        sc += __shfl_xor(sc, 16);
        sc += __shfl_xor(sc, 32);
        if (lane < 16) atomicAdd(&cnt[ntq * 16 + lane], sc);
    }
#undef LOADM
#undef WRITEM
}

// ---------------------------------------------------------------------------
// BN of binary spikes; spk2h is [B][8][HW][16].
__global__ __launch_bounds__(256) void bn_step_kernel(
        const u16* __restrict__ spk2h, const int* __restrict__ cnt,
        const float* __restrict__ gamma, const float* __restrict__ bnb,
        float4* __restrict__ out) {
#pragma clang fp contract(off)
    int i = blockIdx.x * 256 + threadIdx.x;        // 589824 quads (ch-major out)
    int e = i * 4;
    int tmp = e / HW;                               // b*128 + c
    int bb = tmp >> 7, c = tmp & 127;
    int hw0 = e - tmp * HW;
    const u16* sp = spk2h + ((size_t)(bb * 8 + (c >> 4)) * HW + hw0) * 16 + (c & 15);
    float mu  = (float)cnt[c] / (float)NPIX;
    float var = mu - mu * mu;
    float rs  = rsqrtf(var + 1e-5f);
    float g = gamma[c], bv = bnb[c];
    float s0 = bff(sp[0]), s1 = bff(sp[16]), s2 = bff(sp[32]), s3 = bff(sp[48]);
    out[i] = make_float4(g * (s0 - mu) * rs + bv, g * (s1 - mu) * rs + bv,
                         g * (s2 - mu) * rs + bv, g * (s3 - mu) * rs + bv);
}

// ---------------------------------------------------------------------------
extern "C" void kernel_launch(void* const* d_in, const int* in_sizes, int n_in,
                              void* d_out, int out_size, void* d_ws, size_t ws_size,
                              hipStream_t stream) {
    const float* x       = (const float*)d_in[0];
    const float* p_alpha = (const float*)d_in[1];
    const float* p_beta  = (const float*)d_in[2];
    const float* p_th1   = (const float*)d_in[3];
    const float* p_th2   = (const float*)d_in[4];
    const float* w_conv  = (const float*)d_in[5];
    const float* b_conv  = (const float*)d_in[6];
    const float* gamma   = (const float*)d_in[7];
    const float* bn_beta = (const float*)d_in[8];
    float* out = (float*)d_out;

    float* wsf   = (float*)d_ws;
    float* syn_e = wsf + OFF_SYNE;
    float* syn_i = wsf + OFF_SYNI;
    u16*   spk1h = (u16*)(wsf + OFF_SPK1H);
    int*   cnt   = (int*)(wsf + OFF_CNT);
    float* syn2  = wsf + OFF_SYN2;
    u16*   spk2h = (u16*)(wsf + OFF_SPK2H);
    u16*   m2buf[2] = {(u16*)(wsf + OFF_M2H0), (u16*)(wsf + OFF_M2H1)};
    u16*   wt    = (u16*)(wsf + OFF_WT);
    float* u     = wsf + OFF_U;

    zero_ws_kernel<<<ZERO_W / 256, 256, 0, stream>>>(wsf, ZERO_W);
    wt_transform_kernel<<<432, 256, 0, stream>>>(w_conv, wt);

    // ---- t = 0 (algebraic) ----
    alpha_step_kernel<<<1152, 256, 0, stream>>>(
        (const float4*)x, p_alpha, p_beta, p_th1,
        (float4*)syn_e, (float4*)syn_i, spk1h);
    t0_u_kernel<<<1, COUT, 0, stream>>>(b_conv, u);
    t0_fillA_kernel<<<2304, 256, 0, stream>>>(u, bn_beta, (float4*)out);
    t0_fillB_kernel<<<2304, 256, 0, stream>>>(u, m2buf[0], (float4*)syn2);

    // ---- t = 1..3 ----
    for (int t = 1; t < T_; ++t) {
        const int rd = (t - 1) & 1, wr = t & 1;
        alpha_step_kernel<<<1152, 256, 0, stream>>>(
            (const float4*)(x + (size_t)t * 1179648), p_alpha, p_beta, p_th1,
            (float4*)syn_e, (float4*)syn_i, spk1h);
        conv_lstm_fused<<<1152, 256, 0, stream>>>(
            spk1h, m2buf[rd], wt, b_conv, p_th2,
            syn2, m2buf[wr], spk2h, cnt + t * COUT);
        bn_step_kernel<<<2304, 256, 0, stream>>>(
            spk2h, cnt + t * COUT, gamma, bn_beta,
            (float4*)(out + (size_t)t * 2359296));
    }
}